// Round 7
// baseline (1243.717 us; speedup 1.0000x reference)
//
#include <hip/hip_runtime.h>
#include <stdint.h>

typedef _Float16 f16x8 __attribute__((ext_vector_type(8)));
typedef float    f32x4 __attribute__((ext_vector_type(4)));
typedef unsigned u32x4 __attribute__((ext_vector_type(4)));
typedef unsigned u32x2 __attribute__((ext_vector_type(2)));

union Frag {
  u32x4 q;
  f16x8 h;
  unsigned u[4];
};

static __device__ __forceinline__ unsigned short f2h(float f) {
  _Float16 h = (_Float16)f;
  return __builtin_bit_cast(unsigned short, h);
}
static __device__ __forceinline__ unsigned packhf(float lo, float hi) {
  _Float16 a = (_Float16)lo, b = (_Float16)hi;
  unsigned short x = __builtin_bit_cast(unsigned short, a);
  unsigned short y = __builtin_bit_cast(unsigned short, b);
  return (unsigned)x | ((unsigned)y << 16);
}

// decode 8 features: two biased-u8 words per table + 2-bit-sum nibbles in spr.
// h = max( 2*(q8a+q8b) + ba + bb - 512, 0 ), integer in [0,508].
static __device__ __forceinline__ void dec8(u32x2 ua, u32x2 ub, unsigned spr, Frag& f) {
  #pragma unroll
  for (int w = 0; w < 2; ++w) {
    unsigned a = ua[w], b = ub[w];
    unsigned lo = (a & 0x00FF00FFu) + (b & 0x00FF00FFu);          // p0,p2 (+256)
    unsigned hi = ((a >> 8) & 0x00FF00FFu) + ((b >> 8) & 0x00FF00FFu); // p1,p3
    int h0 = ((int)(lo & 0xFFFFu) << 1) + (int)((spr >> (16*w + 0))  & 3u) - 512;
    int h1 = ((int)(hi & 0xFFFFu) << 1) + (int)((spr >> (16*w + 4))  & 3u) - 512;
    int h2 = ((int)(lo >> 16)     << 1) + (int)((spr >> (16*w + 8))  & 3u) - 512;
    int h3 = ((int)(hi >> 16)     << 1) + (int)((spr >> (16*w + 12)) & 3u) - 512;
    h0 = h0 > 0 ? h0 : 0;  h1 = h1 > 0 ? h1 : 0;
    h2 = h2 > 0 ? h2 : 0;  h3 = h3 > 0 ? h3 : 0;
    f.u[2*w]   = packhf((float)h0, (float)h1);
    f.u[2*w+1] = packhf((float)h2, (float)h3);
  }
}
static __device__ __forceinline__ void dec8i(u32x2 ua, u32x2 ub, unsigned spr, int* h) {
  #pragma unroll
  for (int w = 0; w < 2; ++w) {
    unsigned a = ua[w], b = ub[w];
    unsigned lo = (a & 0x00FF00FFu) + (b & 0x00FF00FFu);
    unsigned hi = ((a >> 8) & 0x00FF00FFu) + ((b >> 8) & 0x00FF00FFu);
    int h0 = ((int)(lo & 0xFFFFu) << 1) + (int)((spr >> (16*w + 0))  & 3u) - 512;
    int h1 = ((int)(hi & 0xFFFFu) << 1) + (int)((spr >> (16*w + 4))  & 3u) - 512;
    int h2 = ((int)(lo >> 16)     << 1) + (int)((spr >> (16*w + 8))  & 3u) - 512;
    int h3 = ((int)(hi >> 16)     << 1) + (int)((spr >> (16*w + 12)) & 3u) - 512;
    h[4*w+0] = h0 > 0 ? h0 : 0;  h[4*w+1] = h1 > 0 ? h1 : 0;
    h[4*w+2] = h2 > 0 ? h2 : 0;  h[4*w+3] = h3 > 0 ? h3 : 0;
  }
}

// ---------------- kernel 1: per-node projections (2 passes) -----------
// STORE=0: compute T1/T2 values, track per-feature max|.| -> gmax (atomics).
// STORE=1: recompute identically, quantize to 9-bit (u8 + bit plane).
template<int STORE>
__global__ __launch_bounds__(256) void k_nodeproj(
    const float* __restrict__ z, const float* __restrict__ c,
    const float* __restrict__ W1, const float* __restrict__ b1,
    const float* __restrict__ dinv, unsigned* __restrict__ gmax1,
    unsigned* __restrict__ gmax2, unsigned char* __restrict__ U1,
    unsigned char* __restrict__ U2, unsigned char* __restrict__ V1,
    unsigned char* __restrict__ V2, int n_nodes) {
  __shared__ float Wl[64][128];   // 32 KB
  __shared__ float kv[128];
  __shared__ unsigned lmx[2][128];
  __shared__ float di[128];
  const int t = threadIdx.x;
  if (STORE) {
    if (t < 128) di[t] = dinv[t];
  } else {
    if (t < 128) { lmx[0][t] = 0u; lmx[1][t] = 0u; }
  }
  if (t < 128) {
    float acc = b1[t];
    #pragma unroll
    for (int q = 0; q < 4; ++q) acc += c[q] * W1[(128 + q) * 128 + t];
    kv[t] = acc;
  }
  for (int i = t; i < 8192; i += 256) Wl[i >> 7][i & 127] = W1[i];
  __syncthreads();
  const int n = blockIdx.x * 256 + t;
  const bool act = (n < n_nodes);
  float zr[64];
  if (act) {
    const f32x4* zp = (const f32x4*)(z + (size_t)n * 64);
    #pragma unroll
    for (int j = 0; j < 16; ++j) {
      f32x4 v = zp[j];
      zr[4*j+0] = v[0]; zr[4*j+1] = v[1]; zr[4*j+2] = v[2]; zr[4*j+3] = v[3];
    }
  }
  if (act) {
    for (int k8 = 0; k8 < 16; ++k8) {
      float acc[8];
      #pragma unroll
      for (int j = 0; j < 8; ++j) acc[j] = kv[k8*8 + j];
      #pragma unroll
      for (int d = 0; d < 64; ++d) {
        float zd = zr[d];
        f32x4 wa = *(const f32x4*)&Wl[d][k8*8];
        f32x4 wb = *(const f32x4*)&Wl[d][k8*8+4];
        acc[0] += zd*wa[0]; acc[1] += zd*wa[1]; acc[2] += zd*wa[2]; acc[3] += zd*wa[3];
        acc[4] += zd*wb[0]; acc[5] += zd*wb[1]; acc[6] += zd*wb[2]; acc[7] += zd*wb[3];
      }
      if (STORE) {
        unsigned w0 = 0, w1 = 0, bits = 0;
        #pragma unroll
        for (int j = 0; j < 8; ++j) {
          int q9 = (int)rintf(acc[j] * di[k8*8 + j]);
          q9 = q9 > 254 ? 254 : (q9 < -254 ? -254 : q9);
          int bb = q9 & 1;
          int q8 = (q9 - bb) >> 1;
          unsigned by = (unsigned)(q8 + 128);
          if (j < 4) w0 |= by << (8*j); else w1 |= by << (8*(j-4));
          bits |= (unsigned)bb << j;
        }
        u32x2 vv; vv[0] = w0; vv[1] = w1;
        *(u32x2*)(U1 + (size_t)n*128 + k8*8) = vv;
        V1[(size_t)n*16 + k8] = (unsigned char)bits;
      } else {
        #pragma unroll
        for (int j = 0; j < 8; ++j)
          atomicMax(&lmx[0][k8*8 + j], __float_as_uint(fabsf(acc[j])));
      }
    }
  }
  __syncthreads();
  for (int i = t; i < 8192; i += 256) Wl[i >> 7][i & 127] = W1[8192 + i];
  __syncthreads();
  if (act) {
    for (int k8 = 0; k8 < 16; ++k8) {
      float acc[8] = {0,0,0,0,0,0,0,0};
      #pragma unroll
      for (int d = 0; d < 64; ++d) {
        float zd = zr[d];
        f32x4 wa = *(const f32x4*)&Wl[d][k8*8];
        f32x4 wb = *(const f32x4*)&Wl[d][k8*8+4];
        acc[0] += zd*wa[0]; acc[1] += zd*wa[1]; acc[2] += zd*wa[2]; acc[3] += zd*wa[3];
        acc[4] += zd*wb[0]; acc[5] += zd*wb[1]; acc[6] += zd*wb[2]; acc[7] += zd*wb[3];
      }
      if (STORE) {
        unsigned w0 = 0, w1 = 0, bits = 0;
        #pragma unroll
        for (int j = 0; j < 8; ++j) {
          int q9 = (int)rintf(acc[j] * di[k8*8 + j]);
          q9 = q9 > 254 ? 254 : (q9 < -254 ? -254 : q9);
          int bb = q9 & 1;
          int q8 = (q9 - bb) >> 1;
          unsigned by = (unsigned)(q8 + 128);
          if (j < 4) w0 |= by << (8*j); else w1 |= by << (8*(j-4));
          bits |= (unsigned)bb << j;
        }
        u32x2 vv; vv[0] = w0; vv[1] = w1;
        *(u32x2*)(U2 + (size_t)n*128 + k8*8) = vv;
        V2[(size_t)n*16 + k8] = (unsigned char)bits;
      } else {
        #pragma unroll
        for (int j = 0; j < 8; ++j)
          atomicMax(&lmx[1][k8*8 + j], __float_as_uint(fabsf(acc[j])));
      }
    }
  }
  if (!STORE) {
    __syncthreads();
    if (t < 128) {
      atomicMax(&gmax1[t], lmx[0][t]);
      atomicMax(&gmax2[t], lmx[1][t]);
    }
  }
}

// ---------------- kernel 1b: quantization scales ----------------------
__global__ void k_delta(const unsigned* __restrict__ g1, const unsigned* __restrict__ g2,
                        float* __restrict__ delta9, float* __restrict__ dinv) {
  int t = threadIdx.x;
  if (t < 128) {
    float m = fmaxf(__uint_as_float(g1[t]), __uint_as_float(g2[t]));
    m = fmaxf(m, 1e-20f);
    delta9[t] = m * (1.0f / 254.0f);
    dinv[t]   = 254.0f / m;
  }
}

// ---------------- kernel 2: BN statistics (9-bit integer, exact) ------
// 512-thread blocks. Lane (es=l>>4, lm=l&15): edges e8+es, e8+4+es;
// owns features lm*8..+7 -> int sum/sumsq, cross-es shfl reduce.
__global__ __launch_bounds__(512) void k_stats(
    const int* __restrict__ ei, const unsigned char* __restrict__ U1,
    const unsigned char* __restrict__ U2, const unsigned char* __restrict__ V1,
    const unsigned char* __restrict__ V2, int* __restrict__ partial,
    int E, int niter8) {
  __shared__ int red[8][256];
  __shared__ unsigned sprlut[256];
  const int t = threadIdx.x;
  for (int i = t; i < 256; i += 512) {
    unsigned v = 0;
    #pragma unroll
    for (int j = 0; j < 8; ++j) v |= ((unsigned)(i >> j) & 1u) << (4*j);
    sprlut[i] = v;
  }
  __syncthreads();
  const int w = t >> 6, l = t & 63;
  const int es = l >> 4, lm = l & 15;
  const int vw = lm >> 2, vb = (lm & 3) * 8;
  int sm[8] = {0,0,0,0,0,0,0,0};
  int sq[8] = {0,0,0,0,0,0,0,0};
  const int nw = gridDim.x * 8;
  for (int it = blockIdx.x * 8 + w; it < niter8; it += nw) {
    const int e8 = it * 8;
    int s0 = ei[e8 + es],     d0 = ei[E + e8 + es];
    int s1 = ei[e8 + 4 + es], d1 = ei[E + e8 + 4 + es];
    u32x2 a0 = *(const u32x2*)(U1 + (size_t)s0*128 + lm*8);
    u32x2 b0 = *(const u32x2*)(U2 + (size_t)d0*128 + lm*8);
    u32x2 a1 = *(const u32x2*)(U1 + (size_t)s1*128 + lm*8);
    u32x2 b1 = *(const u32x2*)(U2 + (size_t)d1*128 + lm*8);
    unsigned va0 = *(const unsigned*)(V1 + (size_t)s0*16 + vw*4);
    unsigned wb0 = *(const unsigned*)(V2 + (size_t)d0*16 + vw*4);
    unsigned va1 = *(const unsigned*)(V1 + (size_t)s1*16 + vw*4);
    unsigned wb1 = *(const unsigned*)(V2 + (size_t)d1*16 + vw*4);
    unsigned spr0 = sprlut[(va0 >> vb) & 0xffu] + sprlut[(wb0 >> vb) & 0xffu];
    unsigned spr1 = sprlut[(va1 >> vb) & 0xffu] + sprlut[(wb1 >> vb) & 0xffu];
    int h[8];
    dec8i(a0, b0, spr0, h);
    #pragma unroll
    for (int q = 0; q < 8; ++q) { sm[q] += h[q]; sq[q] += h[q]*h[q]; }
    dec8i(a1, b1, spr1, h);
    #pragma unroll
    for (int q = 0; q < 8; ++q) { sm[q] += h[q]; sq[q] += h[q]*h[q]; }
  }
  #pragma unroll
  for (int q = 0; q < 8; ++q) {
    sm[q] += __shfl_xor(sm[q], 16, 64);
    sm[q] += __shfl_xor(sm[q], 32, 64);
    sq[q] += __shfl_xor(sq[q], 16, 64);
    sq[q] += __shfl_xor(sq[q], 32, 64);
  }
  if (es == 0) {
    #pragma unroll
    for (int q = 0; q < 8; ++q) {
      red[w][lm*8 + q]       = sm[q];
      red[w][128 + lm*8 + q] = sq[q];
    }
  }
  __syncthreads();
  if (t < 256) {
    int s = 0;
    #pragma unroll
    for (int ww = 0; ww < 8; ++ww) s += red[ww][t];
    partial[(size_t)blockIdx.x * 256 + t] = s;
  }
}

// ---------------- kernel 3: finalize BN + fold scales into W2 ---------
__global__ __launch_bounds__(1024) void k_finalize(
    const int* __restrict__ partial, int nb,
    const float* __restrict__ gamma, const float* __restrict__ beta,
    const float* __restrict__ W2, const float* __restrict__ b2,
    const float* __restrict__ delta9,
    unsigned short* __restrict__ W2t, float* __restrict__ b2p, double Einv) {
  __shared__ double redd[4][256];
  __shared__ double stat[256];
  __shared__ float ajd[128], bbj[128];
  __shared__ float bacc[8][128];
  const int t = threadIdx.x;
  const int slot = t & 255, g = t >> 8;
  double s = 0.0;
  for (int b = g; b < nb; b += 4) s += (double)partial[(size_t)b * 256 + slot];
  redd[g][slot] = s;
  __syncthreads();
  if (t < 256) stat[t] = redd[0][t] + redd[1][t] + redd[2][t] + redd[3][t];
  __syncthreads();
  if (t < 128) {
    double d9 = (double)delta9[t];
    double mean = d9 * stat[t] * Einv;
    double ex2  = d9 * d9 * stat[128 + t] * Einv;
    double var  = ex2 - mean * mean;
    float a = (float)((double)gamma[t] / sqrt(var + 1e-5));
    ajd[t] = a * (float)d9;                 // folds delta into W2t (A-frags are q9 ints)
    bbj[t] = beta[t] - (float)mean * a;
  }
  __syncthreads();
  for (int cidx = t; cidx < 16384; cidx += 1024) {
    int i = cidx >> 7;     // input feature (W2 row)
    int j = cidx & 127;    // output column (W2t row)
    W2t[j * 128 + i] = f2h(ajd[i] * W2[cidx]);
  }
  {
    const int col = t & 127, g2 = t >> 7;
    float acc = 0.f;
    #pragma unroll
    for (int q = 0; q < 16; ++q) {
      int i = g2 * 16 + q;
      acc += bbj[i] * W2[i * 128 + col];
    }
    bacc[g2][col] = acc;
  }
  __syncthreads();
  if (t < 128) {
    float a = b2[t];
    #pragma unroll
    for (int g3 = 0; g3 < 8; ++g3) a += bacc[g3][t];
    b2p[t] = a;
  }
}

// ---------------- kernel 4: per-edge MFMA pass (9-bit, prefetched) ----
__global__ __launch_bounds__(256) void k_edge(
    const int* __restrict__ ei, const unsigned char* __restrict__ U1,
    const unsigned char* __restrict__ U2, const unsigned char* __restrict__ V1,
    const unsigned char* __restrict__ V2, const unsigned short* __restrict__ W2t,
    const float* __restrict__ b2p, const float* __restrict__ W3,
    const float* __restrict__ b3, float* __restrict__ out,
    int E, int ntiles) {
  __shared__ u32x4 w2l[2048];       // 32 KB, XOR-swizzled [n][k] f16
  __shared__ unsigned sprlut[256];
  const int t = threadIdx.x;
  for (int cchunk = t; cchunk < 2048; cchunk += 256) {
    int n = cchunk >> 4;
    int koff = (cchunk & 15) << 4;
    int swz = koff ^ ((n & 7) << 4);
    w2l[n*16 + (swz >> 4)] =
        *(const u32x4*)((const char*)W2t + (size_t)n*256 + koff);
  }
  for (int i = t; i < 256; i += 256) {
    unsigned v = 0;
    #pragma unroll
    for (int j = 0; j < 8; ++j) v |= ((unsigned)(i >> j) & 1u) << (4*j);
    sprlut[i] = v;
  }
  __syncthreads();
  const int w = t >> 6, l = t & 63;
  const int lm = l & 15, lg = l >> 4;
  const int lgs = lg * 8;
  float b2r[8], w3r[8];
  #pragma unroll
  for (int nt = 0; nt < 8; ++nt) {
    b2r[nt] = b2p[nt*16 + lm];
    w3r[nt] = W3[nt*16 + lm];
  }
  const float b3v = *b3;
  const int stride = gridDim.x;
  int tile = blockIdx.x;
  if (tile >= ntiles) return;
  int ebase = tile*128 + w*32;
  u32x2 ua0[4], ua1[4], ub0[4], ub1[4];
  unsigned va0[4], vb0[4], va1[4], vb1[4];
  {
    int src0 = ei[ebase + lm],     src1 = ei[ebase + 16 + lm];
    int dst0 = ei[E + ebase + lm], dst1 = ei[E + ebase + 16 + lm];
    #pragma unroll
    for (int s = 0; s < 4; ++s) {
      const int o = s*32 + lg*8;
      ua0[s] = *(const u32x2*)(U1 + (size_t)src0*128 + o);
      ub0[s] = *(const u32x2*)(U2 + (size_t)dst0*128 + o);
      ua1[s] = *(const u32x2*)(U1 + (size_t)src1*128 + o);
      ub1[s] = *(const u32x2*)(U2 + (size_t)dst1*128 + o);
      va0[s] = *(const unsigned*)(V1 + (size_t)src0*16 + s*4);
      vb0[s] = *(const unsigned*)(V2 + (size_t)dst0*16 + s*4);
      va1[s] = *(const unsigned*)(V1 + (size_t)src1*16 + s*4);
      vb1[s] = *(const unsigned*)(V2 + (size_t)dst1*16 + s*4);
    }
  }
  while (true) {
    const int next = tile + stride;
    const bool has_next = next < ntiles;
    const int pref = has_next ? next : tile;
    const int neb = pref*128 + w*32;
    int nsrc0 = ei[neb + lm],     nsrc1 = ei[neb + 16 + lm];
    int ndst0 = ei[E + neb + lm], ndst1 = ei[E + neb + 16 + lm];
    f32x4 acc[2][8];
    #pragma unroll
    for (int mt = 0; mt < 2; ++mt)
      #pragma unroll
      for (int nt = 0; nt < 8; ++nt) {
        f32x4 zed = {0.f, 0.f, 0.f, 0.f};
        acc[mt][nt] = zed;
      }
    #pragma unroll
    for (int s = 0; s < 4; ++s) {
      // decode current staged s-group -> f16 A fragments
      unsigned spr0 = sprlut[(va0[s] >> lgs) & 0xffu] + sprlut[(vb0[s] >> lgs) & 0xffu];
      unsigned spr1 = sprlut[(va1[s] >> lgs) & 0xffu] + sprlut[(vb1[s] >> lgs) & 0xffu];
      Frag a0, a1;
      dec8(ua0[s], ub0[s], spr0, a0);
      dec8(ua1[s], ub1[s], spr1, a1);
      // re-issue this s-group's gathers for the next tile
      {
        const int o = s*32 + lg*8;
        ua0[s] = *(const u32x2*)(U1 + (size_t)nsrc0*128 + o);
        ub0[s] = *(const u32x2*)(U2 + (size_t)ndst0*128 + o);
        ua1[s] = *(const u32x2*)(U1 + (size_t)nsrc1*128 + o);
        ub1[s] = *(const u32x2*)(U2 + (size_t)ndst1*128 + o);
        va0[s] = *(const unsigned*)(V1 + (size_t)nsrc0*16 + s*4);
        vb0[s] = *(const unsigned*)(V2 + (size_t)ndst0*16 + s*4);
        va1[s] = *(const unsigned*)(V1 + (size_t)nsrc1*16 + s*4);
        vb1[s] = *(const unsigned*)(V2 + (size_t)ndst1*16 + s*4);
      }
      #pragma unroll
      for (int nt = 0; nt < 8; ++nt) {
        int idx16 = (nt*16 + lm)*16 + ((s*4 + lg) ^ (lm & 7));
        Frag bf; bf.q = w2l[idx16];
        acc[0][nt] = __builtin_amdgcn_mfma_f32_16x16x32_f16(a0.h, bf.h, acc[0][nt], 0, 0, 0);
        acc[1][nt] = __builtin_amdgcn_mfma_f32_16x16x32_f16(a1.h, bf.h, acc[1][nt], 0, 0, 0);
      }
    }
    #pragma unroll
    for (int mt = 0; mt < 2; ++mt) {
      #pragma unroll
      for (int r = 0; r < 4; ++r) {
        float sum = 0.f;
        #pragma unroll
        for (int nt = 0; nt < 8; ++nt) {
          float h2 = fmaxf(acc[mt][nt][r] + b2r[nt], 0.f);
          sum += h2 * w3r[nt];
        }
        sum += __shfl_xor(sum, 1, 64);
        sum += __shfl_xor(sum, 2, 64);
        sum += __shfl_xor(sum, 4, 64);
        sum += __shfl_xor(sum, 8, 64);
        if (lm == 0) out[ebase + mt*16 + lg*4 + r] = sum + b3v;
      }
    }
    if (!has_next) break;
    tile = next;
    ebase = neb;
  }
}

extern "C" void kernel_launch(void* const* d_in, const int* in_sizes, int n_in,
                              void* d_out, int out_size, void* d_ws, size_t ws_size,
                              hipStream_t stream) {
  const float* z     = (const float*)d_in[0];
  const int*   ei    = (const int*)d_in[1];
  const float* c     = (const float*)d_in[2];
  const float* W1    = (const float*)d_in[3];
  const float* b1    = (const float*)d_in[4];
  const float* gamma = (const float*)d_in[5];
  const float* beta  = (const float*)d_in[6];
  const float* W2    = (const float*)d_in[7];
  const float* b2    = (const float*)d_in[8];
  const float* W3    = (const float*)d_in[9];
  const float* b3    = (const float*)d_in[10];
  float* out = (float*)d_out;

  const int n_nodes = in_sizes[0] / 64;   // 50000
  const int E       = in_sizes[1] / 2;    // 1600000
  const int NB2 = 1024;

  char* ws = (char*)d_ws;
  const size_t nb128 = (size_t)n_nodes * 128;   // 6,400,000
  const size_t nb16  = (size_t)n_nodes * 16;    //   800,000
  unsigned char* U1 = (unsigned char*)ws;
  unsigned char* U2 = U1 + nb128;
  unsigned char* V1 = U2 + nb128;
  unsigned char* V2 = V1 + nb16;
  char* p = (char*)(V2 + nb16);
  int* partial        = (int*)p;                 p += (size_t)NB2 * 256 * 4;
  unsigned short* W2t = (unsigned short*)p;      p += 32768;
  float* b2p          = (float*)p;               p += 512;
  unsigned* gmax1     = (unsigned*)p;            p += 512;
  unsigned* gmax2     = (unsigned*)p;            p += 512;
  float* delta9       = (float*)p;               p += 512;
  float* dinv         = (float*)p;

  hipMemsetAsync(gmax1, 0, 1024, stream);
  const int npb = (n_nodes + 255) / 256;
  k_nodeproj<0><<<npb, 256, 0, stream>>>(z, c, W1, b1, dinv, gmax1, gmax2,
                                         U1, U2, V1, V2, n_nodes);
  k_delta<<<1, 128, 0, stream>>>(gmax1, gmax2, delta9, dinv);
  k_nodeproj<1><<<npb, 256, 0, stream>>>(z, c, W1, b1, dinv, gmax1, gmax2,
                                         U1, U2, V1, V2, n_nodes);
  k_stats<<<NB2, 512, 0, stream>>>(ei, U1, U2, V1, V2, partial, E, E/8);
  k_finalize<<<1, 1024, 0, stream>>>(partial, NB2, gamma, beta, W2, b2, delta9,
                                     W2t, b2p, 1.0 / (double)E);
  k_edge<<<1024, 256, 0, stream>>>(ei, U1, U2, V1, V2, W2t, b2p, W3, b3, out,
                                   E, E/128);
}

// Round 8
// 491.395 us; speedup vs baseline: 2.5310x; 2.5310x over previous
//
#include <hip/hip_runtime.h>
#include <stdint.h>

typedef _Float16 f16x8 __attribute__((ext_vector_type(8)));
typedef float    f32x4 __attribute__((ext_vector_type(4)));
typedef unsigned u32x4 __attribute__((ext_vector_type(4)));
typedef unsigned u32x2 __attribute__((ext_vector_type(2)));

union Frag {
  u32x4 q;
  f16x8 h;
  unsigned u[4];
};

static __device__ __forceinline__ unsigned short f2h(float f) {
  _Float16 h = (_Float16)f;
  return __builtin_bit_cast(unsigned short, h);
}
static __device__ __forceinline__ unsigned packhf(float lo, float hi) {
  _Float16 a = (_Float16)lo, b = (_Float16)hi;
  unsigned short x = __builtin_bit_cast(unsigned short, a);
  unsigned short y = __builtin_bit_cast(unsigned short, b);
  return (unsigned)x | ((unsigned)y << 16);
}

// decode 8 features: two biased-u8 words per table + 2-bit-sum nibbles in spr.
// h = max( 2*(q8a+q8b) + ba + bb - 512, 0 ), integer in [0,508].
static __device__ __forceinline__ void dec8(u32x2 ua, u32x2 ub, unsigned spr, Frag& f) {
  #pragma unroll
  for (int w = 0; w < 2; ++w) {
    unsigned a = ua[w], b = ub[w];
    unsigned lo = (a & 0x00FF00FFu) + (b & 0x00FF00FFu);          // p0,p2 (+256)
    unsigned hi = ((a >> 8) & 0x00FF00FFu) + ((b >> 8) & 0x00FF00FFu); // p1,p3
    int h0 = ((int)(lo & 0xFFFFu) << 1) + (int)((spr >> (16*w + 0))  & 3u) - 512;
    int h1 = ((int)(hi & 0xFFFFu) << 1) + (int)((spr >> (16*w + 4))  & 3u) - 512;
    int h2 = ((int)(lo >> 16)     << 1) + (int)((spr >> (16*w + 8))  & 3u) - 512;
    int h3 = ((int)(hi >> 16)     << 1) + (int)((spr >> (16*w + 12)) & 3u) - 512;
    h0 = h0 > 0 ? h0 : 0;  h1 = h1 > 0 ? h1 : 0;
    h2 = h2 > 0 ? h2 : 0;  h3 = h3 > 0 ? h3 : 0;
    f.u[2*w]   = packhf((float)h0, (float)h1);
    f.u[2*w+1] = packhf((float)h2, (float)h3);
  }
}
static __device__ __forceinline__ void dec8i(u32x2 ua, u32x2 ub, unsigned spr, int* h) {
  #pragma unroll
  for (int w = 0; w < 2; ++w) {
    unsigned a = ua[w], b = ub[w];
    unsigned lo = (a & 0x00FF00FFu) + (b & 0x00FF00FFu);
    unsigned hi = ((a >> 8) & 0x00FF00FFu) + ((b >> 8) & 0x00FF00FFu);
    int h0 = ((int)(lo & 0xFFFFu) << 1) + (int)((spr >> (16*w + 0))  & 3u) - 512;
    int h1 = ((int)(hi & 0xFFFFu) << 1) + (int)((spr >> (16*w + 4))  & 3u) - 512;
    int h2 = ((int)(lo >> 16)     << 1) + (int)((spr >> (16*w + 8))  & 3u) - 512;
    int h3 = ((int)(hi >> 16)     << 1) + (int)((spr >> (16*w + 12)) & 3u) - 512;
    h[4*w+0] = h0 > 0 ? h0 : 0;  h[4*w+1] = h1 > 0 ? h1 : 0;
    h[4*w+2] = h2 > 0 ? h2 : 0;  h[4*w+3] = h3 > 0 ? h3 : 0;
  }
}

// ---------------- kernel 1: per-node projections (feature-per-thread) --
// Block: 256 threads, 128 nodes. Thread owns feature j=t&127, node parity
// t>>7. z-tile in LDS (32 KB) read as wave-uniform broadcasts; W1 column j
// in 64 registers (static). STORE=0: per-feature max -> gmax (1 atomic/thr).
// STORE=1: quantize to 9-bit; U byte stored per-thread; V plane via ballot.
template<int STORE>
__global__ __launch_bounds__(256) void k_nodeproj(
    const float* __restrict__ z, const float* __restrict__ c,
    const float* __restrict__ W1, const float* __restrict__ b1,
    const float* __restrict__ dinv, unsigned* __restrict__ gmax1,
    unsigned* __restrict__ gmax2, unsigned char* __restrict__ U1,
    unsigned char* __restrict__ U2, unsigned char* __restrict__ V1,
    unsigned char* __restrict__ V2, int n_nodes) {
  __shared__ float zl[128 * 64];   // 32 KB
  const int t = threadIdx.x;
  const int j = t & 127;           // feature
  const int half = t >> 7;         // node parity
  const int nb = blockIdx.x * 128;
  // stage z-tile (linear, coalesced, guarded)
  {
    const float* zsrc = z + (size_t)nb * 64;
    const int limit = (n_nodes - nb) * 64;   // valid floats in this tile
    for (int i = t; i < 2048; i += 256) {
      f32x4 v = {0.f, 0.f, 0.f, 0.f};
      if (i * 4 + 3 < limit) {
        v = *(const f32x4*)(zsrc + i * 4);
      } else {
        #pragma unroll
        for (int q = 0; q < 4; ++q) if (i * 4 + q < limit) v[q] = zsrc[i * 4 + q];
      }
      *(f32x4*)(zl + i * 4) = v;
    }
  }
  // kv for this feature (c @ W1[128:132] + b1 folded into T1)
  float kvj = b1[j];
  #pragma unroll
  for (int q = 0; q < 4; ++q) kvj += c[q] * W1[(128 + q) * 128 + j];
  const float dij = STORE ? dinv[j] : 0.f;
  __syncthreads();

  float wreg[64];
  // ---- half A: T1 (W1 rows 0..63), bias kvj ----
  #pragma unroll
  for (int d = 0; d < 64; ++d) wreg[d] = W1[d * 128 + j];
  float mx = 0.f;
  for (int i = 0; i < 64; ++i) {
    const int n = i * 2 + half;
    const int gn = nb + n;
    float acc = kvj;
    #pragma unroll
    for (int d4 = 0; d4 < 16; ++d4) {
      f32x4 zz = *(const f32x4*)(zl + n * 64 + d4 * 4);
      acc += zz[0]*wreg[d4*4+0] + zz[1]*wreg[d4*4+1]
           + zz[2]*wreg[d4*4+2] + zz[3]*wreg[d4*4+3];
    }
    if (STORE) {
      int q9 = (int)rintf(acc * dij);
      q9 = q9 > 254 ? 254 : (q9 < -254 ? -254 : q9);
      int bb = q9 & 1;
      unsigned long long mask = __ballot(bb != 0);
      if (gn < n_nodes) {
        U1[(size_t)gn * 128 + j] = (unsigned char)(((q9 - bb) >> 1) + 128);
        if ((t & 63) == 0)
          *(unsigned long long*)(V1 + (size_t)gn * 16 + ((j >> 6) << 3)) = mask;
      }
    } else if (gn < n_nodes) {
      mx = fmaxf(mx, fabsf(acc));
    }
  }
  if (!STORE) atomicMax(&gmax1[j], __float_as_uint(mx));
  // ---- half B: T2 (W1 rows 64..127), no bias ----
  #pragma unroll
  for (int d = 0; d < 64; ++d) wreg[d] = W1[(64 + d) * 128 + j];
  mx = 0.f;
  for (int i = 0; i < 64; ++i) {
    const int n = i * 2 + half;
    const int gn = nb + n;
    float acc = 0.f;
    #pragma unroll
    for (int d4 = 0; d4 < 16; ++d4) {
      f32x4 zz = *(const f32x4*)(zl + n * 64 + d4 * 4);
      acc += zz[0]*wreg[d4*4+0] + zz[1]*wreg[d4*4+1]
           + zz[2]*wreg[d4*4+2] + zz[3]*wreg[d4*4+3];
    }
    if (STORE) {
      int q9 = (int)rintf(acc * dij);
      q9 = q9 > 254 ? 254 : (q9 < -254 ? -254 : q9);
      int bb = q9 & 1;
      unsigned long long mask = __ballot(bb != 0);
      if (gn < n_nodes) {
        U2[(size_t)gn * 128 + j] = (unsigned char)(((q9 - bb) >> 1) + 128);
        if ((t & 63) == 0)
          *(unsigned long long*)(V2 + (size_t)gn * 16 + ((j >> 6) << 3)) = mask;
      }
    } else if (gn < n_nodes) {
      mx = fmaxf(mx, fabsf(acc));
    }
  }
  if (!STORE) atomicMax(&gmax2[j], __float_as_uint(mx));
}

// ---------------- kernel 1b: quantization scales ----------------------
__global__ void k_delta(const unsigned* __restrict__ g1, const unsigned* __restrict__ g2,
                        float* __restrict__ delta9, float* __restrict__ dinv) {
  int t = threadIdx.x;
  if (t < 128) {
    float m = fmaxf(__uint_as_float(g1[t]), __uint_as_float(g2[t]));
    m = fmaxf(m, 1e-20f);
    delta9[t] = m * (1.0f / 254.0f);
    dinv[t]   = 254.0f / m;
  }
}

// ---------------- kernel 2: BN statistics (9-bit integer, exact) ------
__global__ __launch_bounds__(512) void k_stats(
    const int* __restrict__ ei, const unsigned char* __restrict__ U1,
    const unsigned char* __restrict__ U2, const unsigned char* __restrict__ V1,
    const unsigned char* __restrict__ V2, int* __restrict__ partial,
    int E, int niter8) {
  __shared__ int red[8][256];
  __shared__ unsigned sprlut[256];
  const int t = threadIdx.x;
  for (int i = t; i < 256; i += 512) {
    unsigned v = 0;
    #pragma unroll
    for (int j = 0; j < 8; ++j) v |= ((unsigned)(i >> j) & 1u) << (4*j);
    sprlut[i] = v;
  }
  __syncthreads();
  const int w = t >> 6, l = t & 63;
  const int es = l >> 4, lm = l & 15;
  const int vw = lm >> 2, vb = (lm & 3) * 8;
  int sm[8] = {0,0,0,0,0,0,0,0};
  int sq[8] = {0,0,0,0,0,0,0,0};
  const int nw = gridDim.x * 8;
  for (int it = blockIdx.x * 8 + w; it < niter8; it += nw) {
    const int e8 = it * 8;
    int s0 = ei[e8 + es],     d0 = ei[E + e8 + es];
    int s1 = ei[e8 + 4 + es], d1 = ei[E + e8 + 4 + es];
    u32x2 a0 = *(const u32x2*)(U1 + (size_t)s0*128 + lm*8);
    u32x2 b0 = *(const u32x2*)(U2 + (size_t)d0*128 + lm*8);
    u32x2 a1 = *(const u32x2*)(U1 + (size_t)s1*128 + lm*8);
    u32x2 b1 = *(const u32x2*)(U2 + (size_t)d1*128 + lm*8);
    unsigned va0 = *(const unsigned*)(V1 + (size_t)s0*16 + vw*4);
    unsigned wb0 = *(const unsigned*)(V2 + (size_t)d0*16 + vw*4);
    unsigned va1 = *(const unsigned*)(V1 + (size_t)s1*16 + vw*4);
    unsigned wb1 = *(const unsigned*)(V2 + (size_t)d1*16 + vw*4);
    unsigned spr0 = sprlut[(va0 >> vb) & 0xffu] + sprlut[(wb0 >> vb) & 0xffu];
    unsigned spr1 = sprlut[(va1 >> vb) & 0xffu] + sprlut[(wb1 >> vb) & 0xffu];
    int h[8];
    dec8i(a0, b0, spr0, h);
    #pragma unroll
    for (int q = 0; q < 8; ++q) { sm[q] += h[q]; sq[q] += h[q]*h[q]; }
    dec8i(a1, b1, spr1, h);
    #pragma unroll
    for (int q = 0; q < 8; ++q) { sm[q] += h[q]; sq[q] += h[q]*h[q]; }
  }
  #pragma unroll
  for (int q = 0; q < 8; ++q) {
    sm[q] += __shfl_xor(sm[q], 16, 64);
    sm[q] += __shfl_xor(sm[q], 32, 64);
    sq[q] += __shfl_xor(sq[q], 16, 64);
    sq[q] += __shfl_xor(sq[q], 32, 64);
  }
  if (es == 0) {
    #pragma unroll
    for (int q = 0; q < 8; ++q) {
      red[w][lm*8 + q]       = sm[q];
      red[w][128 + lm*8 + q] = sq[q];
    }
  }
  __syncthreads();
  if (t < 256) {
    int s = 0;
    #pragma unroll
    for (int ww = 0; ww < 8; ++ww) s += red[ww][t];
    partial[(size_t)blockIdx.x * 256 + t] = s;
  }
}

// ---------------- kernel 3: finalize BN + fold scales into W2 ---------
__global__ __launch_bounds__(1024) void k_finalize(
    const int* __restrict__ partial, int nb,
    const float* __restrict__ gamma, const float* __restrict__ beta,
    const float* __restrict__ W2, const float* __restrict__ b2,
    const float* __restrict__ delta9,
    unsigned short* __restrict__ W2t, float* __restrict__ b2p, double Einv) {
  __shared__ double redd[4][256];
  __shared__ double stat[256];
  __shared__ float ajd[128], bbj[128];
  __shared__ float bacc[8][128];
  const int t = threadIdx.x;
  const int slot = t & 255, g = t >> 8;
  double s = 0.0;
  for (int b = g; b < nb; b += 4) s += (double)partial[(size_t)b * 256 + slot];
  redd[g][slot] = s;
  __syncthreads();
  if (t < 256) stat[t] = redd[0][t] + redd[1][t] + redd[2][t] + redd[3][t];
  __syncthreads();
  if (t < 128) {
    double d9 = (double)delta9[t];
    double mean = d9 * stat[t] * Einv;
    double ex2  = d9 * d9 * stat[128 + t] * Einv;
    double var  = ex2 - mean * mean;
    float a = (float)((double)gamma[t] / sqrt(var + 1e-5));
    ajd[t] = a * (float)d9;                 // folds delta into W2t (A-frags are q9 ints)
    bbj[t] = beta[t] - (float)mean * a;
  }
  __syncthreads();
  for (int cidx = t; cidx < 16384; cidx += 1024) {
    int i = cidx >> 7;     // input feature (W2 row)
    int j = cidx & 127;    // output column (W2t row)
    W2t[j * 128 + i] = f2h(ajd[i] * W2[cidx]);
  }
  {
    const int col = t & 127, g2 = t >> 7;
    float acc = 0.f;
    #pragma unroll
    for (int q = 0; q < 16; ++q) {
      int i = g2 * 16 + q;
      acc += bbj[i] * W2[i * 128 + col];
    }
    bacc[g2][col] = acc;
  }
  __syncthreads();
  if (t < 128) {
    float a = b2[t];
    #pragma unroll
    for (int g3 = 0; g3 < 8; ++g3) a += bacc[g3][t];
    b2p[t] = a;
  }
}

// ---------------- kernel 4: per-edge MFMA pass (9-bit, prefetched) ----
__global__ __launch_bounds__(256) void k_edge(
    const int* __restrict__ ei, const unsigned char* __restrict__ U1,
    const unsigned char* __restrict__ U2, const unsigned char* __restrict__ V1,
    const unsigned char* __restrict__ V2, const unsigned short* __restrict__ W2t,
    const float* __restrict__ b2p, const float* __restrict__ W3,
    const float* __restrict__ b3, float* __restrict__ out,
    int E, int ntiles) {
  __shared__ u32x4 w2l[2048];       // 32 KB, XOR-swizzled [n][k] f16
  __shared__ unsigned sprlut[256];
  const int t = threadIdx.x;
  for (int cchunk = t; cchunk < 2048; cchunk += 256) {
    int n = cchunk >> 4;
    int koff = (cchunk & 15) << 4;
    int swz = koff ^ ((n & 7) << 4);
    w2l[n*16 + (swz >> 4)] =
        *(const u32x4*)((const char*)W2t + (size_t)n*256 + koff);
  }
  for (int i = t; i < 256; i += 256) {
    unsigned v = 0;
    #pragma unroll
    for (int j = 0; j < 8; ++j) v |= ((unsigned)(i >> j) & 1u) << (4*j);
    sprlut[i] = v;
  }
  __syncthreads();
  const int w = t >> 6, l = t & 63;
  const int lm = l & 15, lg = l >> 4;
  const int lgs = lg * 8;
  float b2r[8], w3r[8];
  #pragma unroll
  for (int nt = 0; nt < 8; ++nt) {
    b2r[nt] = b2p[nt*16 + lm];
    w3r[nt] = W3[nt*16 + lm];
  }
  const float b3v = *b3;
  const int stride = gridDim.x;
  int tile = blockIdx.x;
  if (tile >= ntiles) return;
  int ebase = tile*128 + w*32;
  u32x2 ua0[4], ua1[4], ub0[4], ub1[4];
  unsigned va0[4], vb0[4], va1[4], vb1[4];
  {
    int src0 = ei[ebase + lm],     src1 = ei[ebase + 16 + lm];
    int dst0 = ei[E + ebase + lm], dst1 = ei[E + ebase + 16 + lm];
    #pragma unroll
    for (int s = 0; s < 4; ++s) {
      const int o = s*32 + lg*8;
      ua0[s] = *(const u32x2*)(U1 + (size_t)src0*128 + o);
      ub0[s] = *(const u32x2*)(U2 + (size_t)dst0*128 + o);
      ua1[s] = *(const u32x2*)(U1 + (size_t)src1*128 + o);
      ub1[s] = *(const u32x2*)(U2 + (size_t)dst1*128 + o);
      va0[s] = *(const unsigned*)(V1 + (size_t)src0*16 + s*4);
      vb0[s] = *(const unsigned*)(V2 + (size_t)dst0*16 + s*4);
      va1[s] = *(const unsigned*)(V1 + (size_t)src1*16 + s*4);
      vb1[s] = *(const unsigned*)(V2 + (size_t)dst1*16 + s*4);
    }
  }
  while (true) {
    const int next = tile + stride;
    const bool has_next = next < ntiles;
    const int pref = has_next ? next : tile;
    const int neb = pref*128 + w*32;
    int nsrc0 = ei[neb + lm],     nsrc1 = ei[neb + 16 + lm];
    int ndst0 = ei[E + neb + lm], ndst1 = ei[E + neb + 16 + lm];
    f32x4 acc[2][8];
    #pragma unroll
    for (int mt = 0; mt < 2; ++mt)
      #pragma unroll
      for (int nt = 0; nt < 8; ++nt) {
        f32x4 zed = {0.f, 0.f, 0.f, 0.f};
        acc[mt][nt] = zed;
      }
    #pragma unroll
    for (int s = 0; s < 4; ++s) {
      // decode current staged s-group -> f16 A fragments
      unsigned spr0 = sprlut[(va0[s] >> lgs) & 0xffu] + sprlut[(vb0[s] >> lgs) & 0xffu];
      unsigned spr1 = sprlut[(va1[s] >> lgs) & 0xffu] + sprlut[(vb1[s] >> lgs) & 0xffu];
      Frag a0, a1;
      dec8(ua0[s], ub0[s], spr0, a0);
      dec8(ua1[s], ub1[s], spr1, a1);
      // re-issue this s-group's gathers for the next tile
      {
        const int o = s*32 + lg*8;
        ua0[s] = *(const u32x2*)(U1 + (size_t)nsrc0*128 + o);
        ub0[s] = *(const u32x2*)(U2 + (size_t)ndst0*128 + o);
        ua1[s] = *(const u32x2*)(U1 + (size_t)nsrc1*128 + o);
        ub1[s] = *(const u32x2*)(U2 + (size_t)ndst1*128 + o);
        va0[s] = *(const unsigned*)(V1 + (size_t)nsrc0*16 + s*4);
        vb0[s] = *(const unsigned*)(V2 + (size_t)ndst0*16 + s*4);
        va1[s] = *(const unsigned*)(V1 + (size_t)nsrc1*16 + s*4);
        vb1[s] = *(const unsigned*)(V2 + (size_t)ndst1*16 + s*4);
      }
      #pragma unroll
      for (int nt = 0; nt < 8; ++nt) {
        int idx16 = (nt*16 + lm)*16 + ((s*4 + lg) ^ (lm & 7));
        Frag bf; bf.q = w2l[idx16];
        acc[0][nt] = __builtin_amdgcn_mfma_f32_16x16x32_f16(a0.h, bf.h, acc[0][nt], 0, 0, 0);
        acc[1][nt] = __builtin_amdgcn_mfma_f32_16x16x32_f16(a1.h, bf.h, acc[1][nt], 0, 0, 0);
      }
    }
    #pragma unroll
    for (int mt = 0; mt < 2; ++mt) {
      #pragma unroll
      for (int r = 0; r < 4; ++r) {
        float sum = 0.f;
        #pragma unroll
        for (int nt = 0; nt < 8; ++nt) {
          float h2 = fmaxf(acc[mt][nt][r] + b2r[nt], 0.f);
          sum += h2 * w3r[nt];
        }
        sum += __shfl_xor(sum, 1, 64);
        sum += __shfl_xor(sum, 2, 64);
        sum += __shfl_xor(sum, 4, 64);
        sum += __shfl_xor(sum, 8, 64);
        if (lm == 0) out[ebase + mt*16 + lg*4 + r] = sum + b3v;
      }
    }
    if (!has_next) break;
    tile = next;
    ebase = neb;
  }
}

extern "C" void kernel_launch(void* const* d_in, const int* in_sizes, int n_in,
                              void* d_out, int out_size, void* d_ws, size_t ws_size,
                              hipStream_t stream) {
  const float* z     = (const float*)d_in[0];
  const int*   ei    = (const int*)d_in[1];
  const float* c     = (const float*)d_in[2];
  const float* W1    = (const float*)d_in[3];
  const float* b1    = (const float*)d_in[4];
  const float* gamma = (const float*)d_in[5];
  const float* beta  = (const float*)d_in[6];
  const float* W2    = (const float*)d_in[7];
  const float* b2    = (const float*)d_in[8];
  const float* W3    = (const float*)d_in[9];
  const float* b3    = (const float*)d_in[10];
  float* out = (float*)d_out;

  const int n_nodes = in_sizes[0] / 64;   // 50000
  const int E       = in_sizes[1] / 2;    // 1600000
  const int NB2 = 1024;

  char* ws = (char*)d_ws;
  const size_t nb128 = (size_t)n_nodes * 128;   // 6,400,000
  const size_t nb16  = (size_t)n_nodes * 16;    //   800,000
  unsigned char* U1 = (unsigned char*)ws;
  unsigned char* U2 = U1 + nb128;
  unsigned char* V1 = U2 + nb128;
  unsigned char* V2 = V1 + nb16;
  char* p = (char*)(V2 + nb16);
  int* partial        = (int*)p;                 p += (size_t)NB2 * 256 * 4;
  unsigned short* W2t = (unsigned short*)p;      p += 32768;
  float* b2p          = (float*)p;               p += 512;
  unsigned* gmax1     = (unsigned*)p;            p += 512;
  unsigned* gmax2     = (unsigned*)p;            p += 512;
  float* delta9       = (float*)p;               p += 512;
  float* dinv         = (float*)p;

  hipMemsetAsync(gmax1, 0, 1024, stream);
  const int npb = (n_nodes + 127) / 128;
  k_nodeproj<0><<<npb, 256, 0, stream>>>(z, c, W1, b1, dinv, gmax1, gmax2,
                                         U1, U2, V1, V2, n_nodes);
  k_delta<<<1, 128, 0, stream>>>(gmax1, gmax2, delta9, dinv);
  k_nodeproj<1><<<npb, 256, 0, stream>>>(z, c, W1, b1, dinv, gmax1, gmax2,
                                         U1, U2, V1, V2, n_nodes);
  k_stats<<<NB2, 512, 0, stream>>>(ei, U1, U2, V1, V2, partial, E, E/8);
  k_finalize<<<1, 1024, 0, stream>>>(partial, NB2, gamma, beta, W2, b2, delta9,
                                     W2t, b2p, 1.0 / (double)E);
  k_edge<<<1024, 256, 0, stream>>>(ei, U1, U2, V1, V2, W2t, b2p, W3, b3, out,
                                   E, E/128);
}

// Round 9
// 434.726 us; speedup vs baseline: 2.8609x; 1.1304x over previous
//
#include <hip/hip_runtime.h>
#include <stdint.h>

typedef _Float16 f16x8 __attribute__((ext_vector_type(8)));
typedef float    f32x4 __attribute__((ext_vector_type(4)));
typedef unsigned u32x4 __attribute__((ext_vector_type(4)));

union Frag { u32x4 q; f16x8 h; unsigned u[4]; };

static __device__ __forceinline__ unsigned short f2h(float f) {
  _Float16 h = (_Float16)f;
  return __builtin_bit_cast(unsigned short, h);
}
static __device__ __forceinline__ unsigned packhf(float lo, float hi) {
  _Float16 a = (_Float16)lo, b = (_Float16)hi;
  unsigned short x = __builtin_bit_cast(unsigned short, a);
  unsigned short y = __builtin_bit_cast(unsigned short, b);
  return (unsigned)x | ((unsigned)y << 16);
}

// u8 decode: bytes are q+128; h = max(qa+qb, 0) = max(sum-256, 0), int in [0,254]
static __device__ __forceinline__ void dec4i(unsigned a, unsigned b, int* h) {
  unsigned lo = (a & 0x00FF00FFu) + (b & 0x00FF00FFu);
  unsigned hi = ((a >> 8) & 0x00FF00FFu) + ((b >> 8) & 0x00FF00FFu);
  int t0 = (int)(lo & 0xFFFFu) - 256;
  int t1 = (int)(hi & 0xFFFFu) - 256;
  int t2 = (int)(lo >> 16) - 256;
  int t3 = (int)(hi >> 16) - 256;
  h[0] = t0 > 0 ? t0 : 0; h[1] = t1 > 0 ? t1 : 0;
  h[2] = t2 > 0 ? t2 : 0; h[3] = t3 > 0 ? t3 : 0;
}
static __device__ __forceinline__ void dec4f(unsigned a, unsigned b,
                                            unsigned& w0, unsigned& w1) {
  int h[4]; dec4i(a, b, h);
  w0 = packhf((float)h[0], (float)h[1]);
  w1 = packhf((float)h[2], (float)h[3]);
}

// ---------------- kernel 1: per-node projections (feature-per-thread) --
// Thread owns true feature j; stores U byte at permuted pos
// p(f) = ((f>>3)&3)*32 + (f>>5)*8 + (f&7)  (lane-major for 16B frag loads)
template<int STORE>
__global__ __launch_bounds__(256) void k_nodeproj(
    const float* __restrict__ z, const float* __restrict__ c,
    const float* __restrict__ W1, const float* __restrict__ b1,
    const float* __restrict__ dinv, unsigned* __restrict__ gmax1,
    unsigned* __restrict__ gmax2, unsigned char* __restrict__ U1,
    unsigned char* __restrict__ U2, int n_nodes) {
  __shared__ float zl[128 * 64];   // 32 KB
  const int t = threadIdx.x;
  const int j = t & 127;           // true feature
  const int pj = ((j >> 3) & 3) * 32 + (j >> 5) * 8 + (j & 7);  // permuted byte
  const int half = t >> 7;         // node parity
  const int nb = blockIdx.x * 128;
  {
    const float* zsrc = z + (size_t)nb * 64;
    const int limit = (n_nodes - nb) * 64;
    for (int i = t; i < 2048; i += 256) {
      f32x4 v = {0.f, 0.f, 0.f, 0.f};
      if (i * 4 + 3 < limit) {
        v = *(const f32x4*)(zsrc + i * 4);
      } else {
        #pragma unroll
        for (int q = 0; q < 4; ++q) if (i * 4 + q < limit) v[q] = zsrc[i * 4 + q];
      }
      *(f32x4*)(zl + i * 4) = v;
    }
  }
  float kvj = b1[j];
  #pragma unroll
  for (int q = 0; q < 4; ++q) kvj += c[q] * W1[(128 + q) * 128 + j];
  const float dij = STORE ? dinv[j] : 0.f;
  __syncthreads();

  float wreg[64];
  // ---- half A: T1 (W1 rows 0..63), bias kvj ----
  #pragma unroll
  for (int d = 0; d < 64; ++d) wreg[d] = W1[d * 128 + j];
  float mx = 0.f;
  for (int i = 0; i < 64; ++i) {
    const int n = i * 2 + half;
    const int gn = nb + n;
    float acc = kvj;
    #pragma unroll
    for (int d4 = 0; d4 < 16; ++d4) {
      f32x4 zz = *(const f32x4*)(zl + n * 64 + d4 * 4);
      acc += zz[0]*wreg[d4*4+0] + zz[1]*wreg[d4*4+1]
           + zz[2]*wreg[d4*4+2] + zz[3]*wreg[d4*4+3];
    }
    if (STORE) {
      int q8 = (int)rintf(acc * dij);
      q8 = q8 > 127 ? 127 : (q8 < -127 ? -127 : q8);
      if (gn < n_nodes) U1[(size_t)gn * 128 + pj] = (unsigned char)(q8 + 128);
    } else if (gn < n_nodes) {
      mx = fmaxf(mx, fabsf(acc));
    }
  }
  if (!STORE) atomicMax(&gmax1[j], __float_as_uint(mx));
  // ---- half B: T2 (W1 rows 64..127), no bias ----
  #pragma unroll
  for (int d = 0; d < 64; ++d) wreg[d] = W1[(64 + d) * 128 + j];
  mx = 0.f;
  for (int i = 0; i < 64; ++i) {
    const int n = i * 2 + half;
    const int gn = nb + n;
    float acc = 0.f;
    #pragma unroll
    for (int d4 = 0; d4 < 16; ++d4) {
      f32x4 zz = *(const f32x4*)(zl + n * 64 + d4 * 4);
      acc += zz[0]*wreg[d4*4+0] + zz[1]*wreg[d4*4+1]
           + zz[2]*wreg[d4*4+2] + zz[3]*wreg[d4*4+3];
    }
    if (STORE) {
      int q8 = (int)rintf(acc * dij);
      q8 = q8 > 127 ? 127 : (q8 < -127 ? -127 : q8);
      if (gn < n_nodes) U2[(size_t)gn * 128 + pj] = (unsigned char)(q8 + 128);
    } else if (gn < n_nodes) {
      mx = fmaxf(mx, fabsf(acc));
    }
  }
  if (!STORE) atomicMax(&gmax2[j], __float_as_uint(mx));
}

// ---------------- kernel 1b: quantization scales ----------------------
__global__ void k_delta(const unsigned* __restrict__ g1, const unsigned* __restrict__ g2,
                        float* __restrict__ delta8, float* __restrict__ dinv) {
  int t = threadIdx.x;
  if (t < 128) {
    float m = fmaxf(__uint_as_float(g1[t]), __uint_as_float(g2[t]));
    m = fmaxf(m, 1e-20f);
    delta8[t] = m * (1.0f / 127.0f);
    dinv[t]   = 127.0f / m;
  }
}

// ---------------- kernel 2: BN statistics (u8, exact int) -------------
// 512 thr. Lane: es = l>>3 (edge slot), ch = l&7 (16B chunk of the row).
// 16 edges per wave-iter (2 groups of 8). 16 int sum + 16 sumsq per lane.
__global__ __launch_bounds__(512) void k_stats(
    const int* __restrict__ ei, const unsigned char* __restrict__ U1,
    const unsigned char* __restrict__ U2, int* __restrict__ partial,
    int E, int niter16) {
  __shared__ int red[8][256];
  const int t = threadIdx.x;
  const int w = t >> 6, l = t & 63;
  const int es = l >> 3, ch = l & 7;
  int sm[16], sq[16];
  #pragma unroll
  for (int k = 0; k < 16; ++k) { sm[k] = 0; sq[k] = 0; }
  const int nw = gridDim.x * 8;
  for (int it = blockIdx.x * 8 + w; it < niter16; it += nw) {
    const int e16 = it * 16;
    int s0 = ei[e16 + es],     d0 = ei[E + e16 + es];
    int s1 = ei[e16 + 8 + es], d1 = ei[E + e16 + 8 + es];
    u32x4 a0 = *(const u32x4*)(U1 + (size_t)s0 * 128 + ch * 16);
    u32x4 b0 = *(const u32x4*)(U2 + (size_t)d0 * 128 + ch * 16);
    u32x4 a1 = *(const u32x4*)(U1 + (size_t)s1 * 128 + ch * 16);
    u32x4 b1 = *(const u32x4*)(U2 + (size_t)d1 * 128 + ch * 16);
    #pragma unroll
    for (int qq = 0; qq < 4; ++qq) {
      int h[4];
      dec4i(a0[qq], b0[qq], h);
      #pragma unroll
      for (int r = 0; r < 4; ++r) { sm[qq*4+r] += h[r]; sq[qq*4+r] += h[r]*h[r]; }
      dec4i(a1[qq], b1[qq], h);
      #pragma unroll
      for (int r = 0; r < 4; ++r) { sm[qq*4+r] += h[r]; sq[qq*4+r] += h[r]*h[r]; }
    }
  }
  // reduce over the 8 edge-slots (lanes sharing ch differ in bits 3..5)
  #pragma unroll
  for (int k = 0; k < 16; ++k) {
    sm[k] += __shfl_xor(sm[k], 8, 64);
    sm[k] += __shfl_xor(sm[k], 16, 64);
    sm[k] += __shfl_xor(sm[k], 32, 64);
    sq[k] += __shfl_xor(sq[k], 8, 64);
    sq[k] += __shfl_xor(sq[k], 16, 64);
    sq[k] += __shfl_xor(sq[k], 32, 64);
  }
  if (es == 0) {
    #pragma unroll
    for (int k = 0; k < 16; ++k) {
      // true feature of permuted byte p = ch*16 + k
      int f = ((ch & 1) * 2 + (k >> 3)) * 32 + (ch >> 1) * 8 + (k & 7);
      red[w][f]       = sm[k];
      red[w][128 + f] = sq[k];
    }
  }
  __syncthreads();
  if (t < 256) {
    int s = 0;
    #pragma unroll
    for (int ww = 0; ww < 8; ++ww) s += red[ww][t];
    partial[(size_t)blockIdx.x * 256 + t] = s;
  }
}

// ---------------- kernel 3: finalize BN + fold scale into W2 ----------
__global__ __launch_bounds__(1024) void k_finalize(
    const int* __restrict__ partial, int nb,
    const float* __restrict__ gamma, const float* __restrict__ beta,
    const float* __restrict__ W2, const float* __restrict__ b2,
    const float* __restrict__ delta8,
    unsigned short* __restrict__ W2t, float* __restrict__ b2p, double Einv) {
  __shared__ double redd[4][256];
  __shared__ double stat[256];
  __shared__ float ajd[128], bbj[128];
  __shared__ float bacc[8][128];
  const int t = threadIdx.x;
  const int slot = t & 255, g = t >> 8;
  double s = 0.0;
  for (int b = g; b < nb; b += 4) s += (double)partial[(size_t)b * 256 + slot];
  redd[g][slot] = s;
  __syncthreads();
  if (t < 256) stat[t] = redd[0][t] + redd[1][t] + redd[2][t] + redd[3][t];
  __syncthreads();
  if (t < 128) {
    double d8 = (double)delta8[t];
    double mean = d8 * stat[t] * Einv;
    double ex2  = d8 * d8 * stat[128 + t] * Einv;
    double var  = ex2 - mean * mean;
    float a = (float)((double)gamma[t] / sqrt(var + 1e-5));
    ajd[t] = a * (float)d8;                 // A-frags are integer h/delta
    bbj[t] = beta[t] - (float)mean * a;
  }
  __syncthreads();
  for (int cidx = t; cidx < 16384; cidx += 1024) {
    int i = cidx >> 7;     // input feature (W2 row)
    int j = cidx & 127;    // output column (W2t row)
    W2t[j * 128 + i] = f2h(ajd[i] * W2[cidx]);
  }
  {
    const int col = t & 127, g2 = t >> 7;
    float acc = 0.f;
    #pragma unroll
    for (int q = 0; q < 16; ++q) {
      int i = g2 * 16 + q;
      acc += bbj[i] * W2[i * 128 + col];
    }
    bacc[g2][col] = acc;
  }
  __syncthreads();
  if (t < 128) {
    float a = b2[t];
    #pragma unroll
    for (int g3 = 0; g3 < 8; ++g3) a += bacc[g3][t];
    b2p[t] = a;
  }
}

// ---------------- kernel 4: per-edge MFMA pass (u8, prefetched) -------
// Lane (lm,lg): edges ebase+mt*16+lm; 2x16B loads per table per edge cover
// the lane's 4 k-chunks (permuted layout). Decode inline, no LDS LUT.
__global__ __launch_bounds__(256) void k_edge(
    const int* __restrict__ ei, const unsigned char* __restrict__ U1,
    const unsigned char* __restrict__ U2, const unsigned short* __restrict__ W2t,
    const float* __restrict__ b2p, const float* __restrict__ W3,
    const float* __restrict__ b3, float* __restrict__ out,
    int E, int ntiles) {
  __shared__ u32x4 w2l[2048];       // 32 KB, XOR-swizzled [n][k] f16
  const int t = threadIdx.x;
  for (int cchunk = t; cchunk < 2048; cchunk += 256) {
    int n = cchunk >> 4;
    int koff = (cchunk & 15) << 4;
    int swz = koff ^ ((n & 7) << 4);
    w2l[n*16 + (swz >> 4)] =
        *(const u32x4*)((const char*)W2t + (size_t)n*256 + koff);
  }
  __syncthreads();
  const int w = t >> 6, l = t & 63;
  const int lm = l & 15, lg = l >> 4;
  const int lo32 = lg * 32;
  float b2r[8], w3r[8];
  #pragma unroll
  for (int nt = 0; nt < 8; ++nt) {
    b2r[nt] = b2p[nt*16 + lm];
    w3r[nt] = W3[nt*16 + lm];
  }
  const float b3v = *b3;
  const int stride = gridDim.x;
  int tile = blockIdx.x;
  if (tile >= ntiles) return;
  int ebase = tile*128 + w*32;
  // staged rows: X{mt}{half}: halves are bytes [0,16) and [16,32) of lane's 32B
  u32x4 A00, A01, B00, B01, A10, A11, B10, B11;
  {
    int src0 = ei[ebase + lm],     src1 = ei[ebase + 16 + lm];
    int dst0 = ei[E + ebase + lm], dst1 = ei[E + ebase + 16 + lm];
    A00 = *(const u32x4*)(U1 + (size_t)src0*128 + lo32);
    A01 = *(const u32x4*)(U1 + (size_t)src0*128 + lo32 + 16);
    B00 = *(const u32x4*)(U2 + (size_t)dst0*128 + lo32);
    B01 = *(const u32x4*)(U2 + (size_t)dst0*128 + lo32 + 16);
    A10 = *(const u32x4*)(U1 + (size_t)src1*128 + lo32);
    A11 = *(const u32x4*)(U1 + (size_t)src1*128 + lo32 + 16);
    B10 = *(const u32x4*)(U2 + (size_t)dst1*128 + lo32);
    B11 = *(const u32x4*)(U2 + (size_t)dst1*128 + lo32 + 16);
  }
  while (true) {
    const int next = tile + stride;
    const bool has_next = next < ntiles;
    const int pref = has_next ? next : tile;
    const int neb = pref*128 + w*32;
    int nsrc0 = ei[neb + lm],     nsrc1 = ei[neb + 16 + lm];
    int ndst0 = ei[E + neb + lm], ndst1 = ei[E + neb + 16 + lm];
    f32x4 acc[2][8];
    #pragma unroll
    for (int mt = 0; mt < 2; ++mt)
      #pragma unroll
      for (int nt = 0; nt < 8; ++nt) {
        f32x4 zed = {0.f, 0.f, 0.f, 0.f};
        acc[mt][nt] = zed;
      }
    Frag fa0, fa1;
    #define MFMA8(S)                                                        \
      _Pragma("unroll")                                                     \
      for (int nt = 0; nt < 8; ++nt) {                                      \
        int idx16 = (nt*16 + lm)*16 + (((S)*4 + lg) ^ (lm & 7));            \
        Frag bf; bf.q = w2l[idx16];                                         \
        acc[0][nt] = __builtin_amdgcn_mfma_f32_16x16x32_f16(fa0.h, bf.h, acc[0][nt], 0, 0, 0); \
        acc[1][nt] = __builtin_amdgcn_mfma_f32_16x16x32_f16(fa1.h, bf.h, acc[1][nt], 0, 0, 0); \
      }
    // s = 0 (u32s 0,1 of first half)
    dec4f(A00[0], B00[0], fa0.u[0], fa0.u[1]); dec4f(A00[1], B00[1], fa0.u[2], fa0.u[3]);
    dec4f(A10[0], B10[0], fa1.u[0], fa1.u[1]); dec4f(A10[1], B10[1], fa1.u[2], fa1.u[3]);
    MFMA8(0)
    // s = 1 (u32s 2,3) -> first-half regs dead afterwards
    dec4f(A00[2], B00[2], fa0.u[0], fa0.u[1]); dec4f(A00[3], B00[3], fa0.u[2], fa0.u[3]);
    dec4f(A10[2], B10[2], fa1.u[0], fa1.u[1]); dec4f(A10[3], B10[3], fa1.u[2], fa1.u[3]);
    A00 = *(const u32x4*)(U1 + (size_t)nsrc0*128 + lo32);
    B00 = *(const u32x4*)(U2 + (size_t)ndst0*128 + lo32);
    A10 = *(const u32x4*)(U1 + (size_t)nsrc1*128 + lo32);
    B10 = *(const u32x4*)(U2 + (size_t)ndst1*128 + lo32);
    MFMA8(1)
    // s = 2 (second half u32s 0,1)
    dec4f(A01[0], B01[0], fa0.u[0], fa0.u[1]); dec4f(A01[1], B01[1], fa0.u[2], fa0.u[3]);
    dec4f(A11[0], B11[0], fa1.u[0], fa1.u[1]); dec4f(A11[1], B11[1], fa1.u[2], fa1.u[3]);
    MFMA8(2)
    // s = 3 (second half u32s 2,3) -> second-half regs dead afterwards
    dec4f(A01[2], B01[2], fa0.u[0], fa0.u[1]); dec4f(A01[3], B01[3], fa0.u[2], fa0.u[3]);
    dec4f(A11[2], B11[2], fa1.u[0], fa1.u[1]); dec4f(A11[3], B11[3], fa1.u[2], fa1.u[3]);
    A01 = *(const u32x4*)(U1 + (size_t)nsrc0*128 + lo32 + 16);
    B01 = *(const u32x4*)(U2 + (size_t)ndst0*128 + lo32 + 16);
    A11 = *(const u32x4*)(U1 + (size_t)nsrc1*128 + lo32 + 16);
    B11 = *(const u32x4*)(U2 + (size_t)ndst1*128 + lo32 + 16);
    MFMA8(3)
    #undef MFMA8
    // Epilogue: h2 = relu(acc + b2p); logit = sum_n h2*W3 (+b3)
    #pragma unroll
    for (int mt = 0; mt < 2; ++mt) {
      #pragma unroll
      for (int r = 0; r < 4; ++r) {
        float sum = 0.f;
        #pragma unroll
        for (int nt = 0; nt < 8; ++nt) {
          float h2 = fmaxf(acc[mt][nt][r] + b2r[nt], 0.f);
          sum += h2 * w3r[nt];
        }
        sum += __shfl_xor(sum, 1, 64);
        sum += __shfl_xor(sum, 2, 64);
        sum += __shfl_xor(sum, 4, 64);
        sum += __shfl_xor(sum, 8, 64);
        if (lm == 0) out[ebase + mt*16 + lg*4 + r] = sum + b3v;
      }
    }
    if (!has_next) break;
    tile = next;
    ebase = neb;
  }
}

extern "C" void kernel_launch(void* const* d_in, const int* in_sizes, int n_in,
                              void* d_out, int out_size, void* d_ws, size_t ws_size,
                              hipStream_t stream) {
  const float* z     = (const float*)d_in[0];
  const int*   ei    = (const int*)d_in[1];
  const float* c     = (const float*)d_in[2];
  const float* W1    = (const float*)d_in[3];
  const float* b1    = (const float*)d_in[4];
  const float* gamma = (const float*)d_in[5];
  const float* beta  = (const float*)d_in[6];
  const float* W2    = (const float*)d_in[7];
  const float* b2    = (const float*)d_in[8];
  const float* W3    = (const float*)d_in[9];
  const float* b3    = (const float*)d_in[10];
  float* out = (float*)d_out;

  const int n_nodes = in_sizes[0] / 64;   // 50000
  const int E       = in_sizes[1] / 2;    // 1600000
  const int NB2 = 1024;

  char* ws = (char*)d_ws;
  const size_t nb128 = (size_t)n_nodes * 128;   // 6.4 MB per table
  unsigned char* U1 = (unsigned char*)ws;
  unsigned char* U2 = U1 + nb128;
  char* p = (char*)(U2 + nb128);
  int* partial        = (int*)p;                 p += (size_t)NB2 * 256 * 4;
  unsigned short* W2t = (unsigned short*)p;      p += 32768;
  float* b2p          = (float*)p;               p += 512;
  unsigned* gmax1     = (unsigned*)p;            p += 512;
  unsigned* gmax2     = (unsigned*)p;            p += 512;
  float* delta8       = (float*)p;               p += 512;
  float* dinv         = (float*)p;

  hipMemsetAsync(gmax1, 0, 1024, stream);
  const int npb = (n_nodes + 127) / 128;
  k_nodeproj<0><<<npb, 256, 0, stream>>>(z, c, W1, b1, dinv, gmax1, gmax2,
                                         U1, U2, n_nodes);
  k_delta<<<1, 128, 0, stream>>>(gmax1, gmax2, delta8, dinv);
  k_nodeproj<1><<<npb, 256, 0, stream>>>(z, c, W1, b1, dinv, gmax1, gmax2,
                                         U1, U2, n_nodes);
  k_stats<<<NB2, 512, 0, stream>>>(ei, U1, U2, partial, E, E/16);
  k_finalize<<<1, 1024, 0, stream>>>(partial, NB2, gamma, beta, W2, b2, delta8,
                                     W2t, b2p, 1.0 / (double)E);
  k_edge<<<1024, 256, 0, stream>>>(ei, U1, U2, W2t, b2p, W3, b3, out,
                                   E, E/128);
}

// Round 10
// 428.133 us; speedup vs baseline: 2.9050x; 1.0154x over previous
//
#include <hip/hip_runtime.h>
#include <stdint.h>

typedef _Float16 f16x8 __attribute__((ext_vector_type(8)));
typedef float    f32x4 __attribute__((ext_vector_type(4)));
typedef unsigned u32x4 __attribute__((ext_vector_type(4)));

union Frag { u32x4 q; f16x8 h; unsigned u[4]; };

static __device__ __forceinline__ unsigned short f2h(float f) {
  _Float16 h = (_Float16)f;
  return __builtin_bit_cast(unsigned short, h);
}
static __device__ __forceinline__ unsigned packhf(float lo, float hi) {
  _Float16 a = (_Float16)lo, b = (_Float16)hi;
  unsigned short x = __builtin_bit_cast(unsigned short, a);
  unsigned short y = __builtin_bit_cast(unsigned short, b);
  return (unsigned)x | ((unsigned)y << 16);
}

// u8 decode: bytes are q+128; h = max(qa+qb-256, 0), int in [0,254]
static __device__ __forceinline__ void dec4i(unsigned a, unsigned b, int* h) {
  unsigned lo = (a & 0x00FF00FFu) + (b & 0x00FF00FFu);
  unsigned hi = ((a >> 8) & 0x00FF00FFu) + ((b >> 8) & 0x00FF00FFu);
  int t0 = (int)(lo & 0xFFFFu) - 256;
  int t1 = (int)(hi & 0xFFFFu) - 256;
  int t2 = (int)(lo >> 16) - 256;
  int t3 = (int)(hi >> 16) - 256;
  h[0] = t0 > 0 ? t0 : 0; h[1] = t1 > 0 ? t1 : 0;
  h[2] = t2 > 0 ? t2 : 0; h[3] = t3 > 0 ? t3 : 0;
}
static __device__ __forceinline__ void dec4f(unsigned a, unsigned b,
                                            unsigned& w0, unsigned& w1) {
  int h[4]; dec4i(a, b, h);
  w0 = packhf((float)h[0], (float)h[1]);
  w1 = packhf((float)h[2], (float)h[3]);
}
// magic decode for H8 stream: u32 bytes (h_k0,h_k2,h_k1,h_k3) -> two f16 pairs
// holding 1024+h exactly (offset folded into b2ps).
static __device__ __forceinline__ void mg2(unsigned y, unsigned& w0, unsigned& w1) {
  w0 = (y & 0x00FF00FFu) + 0x64006400u;
  w1 = ((y >> 8) & 0x00FF00FFu) + 0x64006400u;
}

// ---------------- kernel 1: per-node projections (feature-per-thread) --
template<int STORE>
__global__ __launch_bounds__(256) void k_nodeproj(
    const float* __restrict__ z, const float* __restrict__ c,
    const float* __restrict__ W1, const float* __restrict__ b1,
    const float* __restrict__ dinv, unsigned* __restrict__ gmax1,
    unsigned* __restrict__ gmax2, unsigned char* __restrict__ U1,
    unsigned char* __restrict__ U2, int n_nodes) {
  __shared__ float zl[128 * 64];   // 32 KB
  const int t = threadIdx.x;
  const int j = t & 127;           // true feature
  const int pj = ((j >> 3) & 3) * 32 + (j >> 5) * 8 + (j & 7);  // permuted byte
  const int half = t >> 7;
  const int nb = blockIdx.x * 128;
  {
    const float* zsrc = z + (size_t)nb * 64;
    const int limit = (n_nodes - nb) * 64;
    for (int i = t; i < 2048; i += 256) {
      f32x4 v = {0.f, 0.f, 0.f, 0.f};
      if (i * 4 + 3 < limit) {
        v = *(const f32x4*)(zsrc + i * 4);
      } else {
        #pragma unroll
        for (int q = 0; q < 4; ++q) if (i * 4 + q < limit) v[q] = zsrc[i * 4 + q];
      }
      *(f32x4*)(zl + i * 4) = v;
    }
  }
  float kvj = b1[j];
  #pragma unroll
  for (int q = 0; q < 4; ++q) kvj += c[q] * W1[(128 + q) * 128 + j];
  const float dij = STORE ? dinv[j] : 0.f;
  __syncthreads();

  float wreg[64];
  #pragma unroll
  for (int d = 0; d < 64; ++d) wreg[d] = W1[d * 128 + j];
  float mx = 0.f;
  for (int i = 0; i < 64; ++i) {
    const int n = i * 2 + half;
    const int gn = nb + n;
    float acc = kvj;
    #pragma unroll
    for (int d4 = 0; d4 < 16; ++d4) {
      f32x4 zz = *(const f32x4*)(zl + n * 64 + d4 * 4);
      acc += zz[0]*wreg[d4*4+0] + zz[1]*wreg[d4*4+1]
           + zz[2]*wreg[d4*4+2] + zz[3]*wreg[d4*4+3];
    }
    if (STORE) {
      int q8 = (int)rintf(acc * dij);
      q8 = q8 > 127 ? 127 : (q8 < -127 ? -127 : q8);
      if (gn < n_nodes) U1[(size_t)gn * 128 + pj] = (unsigned char)(q8 + 128);
    } else if (gn < n_nodes) {
      mx = fmaxf(mx, fabsf(acc));
    }
  }
  if (!STORE) atomicMax(&gmax1[j], __float_as_uint(mx));
  #pragma unroll
  for (int d = 0; d < 64; ++d) wreg[d] = W1[(64 + d) * 128 + j];
  mx = 0.f;
  for (int i = 0; i < 64; ++i) {
    const int n = i * 2 + half;
    const int gn = nb + n;
    float acc = 0.f;
    #pragma unroll
    for (int d4 = 0; d4 < 16; ++d4) {
      f32x4 zz = *(const f32x4*)(zl + n * 64 + d4 * 4);
      acc += zz[0]*wreg[d4*4+0] + zz[1]*wreg[d4*4+1]
           + zz[2]*wreg[d4*4+2] + zz[3]*wreg[d4*4+3];
    }
    if (STORE) {
      int q8 = (int)rintf(acc * dij);
      q8 = q8 > 127 ? 127 : (q8 < -127 ? -127 : q8);
      if (gn < n_nodes) U2[(size_t)gn * 128 + pj] = (unsigned char)(q8 + 128);
    } else if (gn < n_nodes) {
      mx = fmaxf(mx, fabsf(acc));
    }
  }
  if (!STORE) atomicMax(&gmax2[j], __float_as_uint(mx));
}

// ---------------- kernel 1b: quantization scales ----------------------
__global__ void k_delta(const unsigned* __restrict__ g1, const unsigned* __restrict__ g2,
                        float* __restrict__ delta8, float* __restrict__ dinv) {
  int t = threadIdx.x;
  if (t < 128) {
    float m = fmaxf(__uint_as_float(g1[t]), __uint_as_float(g2[t]));
    m = fmaxf(m, 1e-20f);
    delta8[t] = m * (1.0f / 127.0f);
    dinv[t]   = 127.0f / m;
  }
}

// ---------------- kernel 2: BN statistics (u8, exact int) -------------
// WH8: additionally materialize h1 rows (bytes reordered h0,h2,h1,h3 per u32).
template<int WH8>
__global__ __launch_bounds__(512) void k_stats(
    const int* __restrict__ ei, const unsigned char* __restrict__ U1,
    const unsigned char* __restrict__ U2, int* __restrict__ partial,
    unsigned char* __restrict__ H8, int E, int niter16) {
  __shared__ int red[8][256];
  const int t = threadIdx.x;
  const int w = t >> 6, l = t & 63;
  const int es = l >> 3, ch = l & 7;
  int sm[16], sq[16];
  #pragma unroll
  for (int k = 0; k < 16; ++k) { sm[k] = 0; sq[k] = 0; }
  const int nw = gridDim.x * 8;
  for (int it = blockIdx.x * 8 + w; it < niter16; it += nw) {
    const int e16 = it * 16;
    int s0 = ei[e16 + es],     d0 = ei[E + e16 + es];
    int s1 = ei[e16 + 8 + es], d1 = ei[E + e16 + 8 + es];
    u32x4 a0 = *(const u32x4*)(U1 + (size_t)s0 * 128 + ch * 16);
    u32x4 b0 = *(const u32x4*)(U2 + (size_t)d0 * 128 + ch * 16);
    u32x4 a1 = *(const u32x4*)(U1 + (size_t)s1 * 128 + ch * 16);
    u32x4 b1 = *(const u32x4*)(U2 + (size_t)d1 * 128 + ch * 16);
    u32x4 o0, o1;
    #pragma unroll
    for (int qq = 0; qq < 4; ++qq) {
      int h[4];
      dec4i(a0[qq], b0[qq], h);
      #pragma unroll
      for (int r = 0; r < 4; ++r) { sm[qq*4+r] += h[r]; sq[qq*4+r] += h[r]*h[r]; }
      if (WH8) o0[qq] = (unsigned)h[0] | ((unsigned)h[2] << 8)
                      | ((unsigned)h[1] << 16) | ((unsigned)h[3] << 24);
      dec4i(a1[qq], b1[qq], h);
      #pragma unroll
      for (int r = 0; r < 4; ++r) { sm[qq*4+r] += h[r]; sq[qq*4+r] += h[r]*h[r]; }
      if (WH8) o1[qq] = (unsigned)h[0] | ((unsigned)h[2] << 8)
                      | ((unsigned)h[1] << 16) | ((unsigned)h[3] << 24);
    }
    if (WH8) {
      *(u32x4*)(H8 + (size_t)(e16 + es) * 128 + ch * 16)     = o0;
      *(u32x4*)(H8 + (size_t)(e16 + 8 + es) * 128 + ch * 16) = o1;
    }
  }
  #pragma unroll
  for (int k = 0; k < 16; ++k) {
    sm[k] += __shfl_xor(sm[k], 8, 64);
    sm[k] += __shfl_xor(sm[k], 16, 64);
    sm[k] += __shfl_xor(sm[k], 32, 64);
    sq[k] += __shfl_xor(sq[k], 8, 64);
    sq[k] += __shfl_xor(sq[k], 16, 64);
    sq[k] += __shfl_xor(sq[k], 32, 64);
  }
  if (es == 0) {
    #pragma unroll
    for (int k = 0; k < 16; ++k) {
      int f = ((ch & 1) * 2 + (k >> 3)) * 32 + (ch >> 1) * 8 + (k & 7);
      red[w][f]       = sm[k];
      red[w][128 + f] = sq[k];
    }
  }
  __syncthreads();
  if (t < 256) {
    int s = 0;
    #pragma unroll
    for (int ww = 0; ww < 8; ++ww) s += red[ww][t];
    partial[(size_t)blockIdx.x * 256 + t] = s;
  }
}

// ---------------- kernel 3: finalize BN + fold scale into W2 ----------
__global__ __launch_bounds__(1024) void k_finalize(
    const int* __restrict__ partial, int nb,
    const float* __restrict__ gamma, const float* __restrict__ beta,
    const float* __restrict__ W2, const float* __restrict__ b2,
    const float* __restrict__ delta8,
    unsigned short* __restrict__ W2t, float* __restrict__ b2p,
    float* __restrict__ b2ps, double Einv) {
  __shared__ double redd[4][256];
  __shared__ double stat[256];
  __shared__ float ajd[128], bbj[128];
  __shared__ float bacc[8][128];
  const int t = threadIdx.x;
  const int slot = t & 255, g = t >> 8;
  double s = 0.0;
  for (int b = g; b < nb; b += 4) s += (double)partial[(size_t)b * 256 + slot];
  redd[g][slot] = s;
  __syncthreads();
  if (t < 256) stat[t] = redd[0][t] + redd[1][t] + redd[2][t] + redd[3][t];
  __syncthreads();
  if (t < 128) {
    double d8 = (double)delta8[t];
    double mean = d8 * stat[t] * Einv;
    double ex2  = d8 * d8 * stat[128 + t] * Einv;
    double var  = ex2 - mean * mean;
    float a = (float)((double)gamma[t] / sqrt(var + 1e-5));
    ajd[t] = a * (float)d8;
    bbj[t] = beta[t] - (float)mean * a;
  }
  __syncthreads();
  for (int cidx = t; cidx < 16384; cidx += 1024) {
    int i = cidx >> 7;
    int j = cidx & 127;
    W2t[j * 128 + i] = f2h(ajd[i] * W2[cidx]);
  }
  {
    const int col = t & 127, g2 = t >> 7;
    float acc = 0.f;
    #pragma unroll
    for (int q = 0; q < 16; ++q) {
      int i = g2 * 16 + q;
      acc += bbj[i] * W2[i * 128 + col];
    }
    bacc[g2][col] = acc;
  }
  __syncthreads();
  if (t < 128) {
    float a = b2[t];
    #pragma unroll
    for (int g3 = 0; g3 < 8; ++g3) a += bacc[g3][t];
    b2p[t] = a;
    // correction for magic-bias stream decode (A fed as 1024+h):
    // c = sum_i f16(ajd[i]*W2[i][t]) recomputed (matches W2t rounding)
    float c = 0.f;
    for (int i = 0; i < 128; ++i)
      c += (float)((_Float16)(ajd[i] * W2[i * 128 + t]));
    b2ps[t] = a - 1024.0f * c;
  }
}

// ---------------- kernel 4a: streaming MFMA over materialized H8 ------
__global__ __launch_bounds__(256) void k_edge_h8(
    const unsigned char* __restrict__ H8, const unsigned short* __restrict__ W2t,
    const float* __restrict__ b2ps, const float* __restrict__ W3,
    const float* __restrict__ b3, float* __restrict__ out, int ntiles) {
  __shared__ u32x4 w2l[2048];
  const int t = threadIdx.x;
  for (int cchunk = t; cchunk < 2048; cchunk += 256) {
    int n = cchunk >> 4;
    int koff = (cchunk & 15) << 4;
    int swz = koff ^ ((n & 7) << 4);
    w2l[n*16 + (swz >> 4)] =
        *(const u32x4*)((const char*)W2t + (size_t)n*256 + koff);
  }
  __syncthreads();
  const int w = t >> 6, l = t & 63;
  const int lm = l & 15, lg = l >> 4;
  const int lo32 = lg * 32;
  float b2r[8], w3r[8];
  #pragma unroll
  for (int nt = 0; nt < 8; ++nt) {
    b2r[nt] = b2ps[nt*16 + lm];
    w3r[nt] = W3[nt*16 + lm];
  }
  const float b3v = *b3;
  const int stride = gridDim.x;
  int tile = blockIdx.x;
  if (tile >= ntiles) return;
  int ebase = tile*128 + w*32;
  u32x4 Y00, Y01, Y10, Y11;   // edge lm (mt0) / lm+16 (mt1), two 16B halves
  {
    const unsigned char* r0 = H8 + (size_t)(ebase + lm) * 128 + lo32;
    const unsigned char* r1 = H8 + (size_t)(ebase + 16 + lm) * 128 + lo32;
    Y00 = *(const u32x4*)r0;  Y01 = *(const u32x4*)(r0 + 16);
    Y10 = *(const u32x4*)r1;  Y11 = *(const u32x4*)(r1 + 16);
  }
  while (true) {
    const int next = tile + stride;
    const bool has_next = next < ntiles;
    const int pref = has_next ? next : tile;
    const int neb = pref*128 + w*32;
    const unsigned char* n0 = H8 + (size_t)(neb + lm) * 128 + lo32;
    const unsigned char* n1 = H8 + (size_t)(neb + 16 + lm) * 128 + lo32;
    f32x4 acc[2][8];
    #pragma unroll
    for (int mt = 0; mt < 2; ++mt)
      #pragma unroll
      for (int nt = 0; nt < 8; ++nt) {
        f32x4 zed = {0.f, 0.f, 0.f, 0.f};
        acc[mt][nt] = zed;
      }
    Frag fa0, fa1;
    #define MFMA8S(S)                                                       \
      _Pragma("unroll")                                                     \
      for (int nt = 0; nt < 8; ++nt) {                                      \
        int idx16 = (nt*16 + lm)*16 + (((S)*4 + lg) ^ (lm & 7));            \
        Frag bf; bf.q = w2l[idx16];                                         \
        acc[0][nt] = __builtin_amdgcn_mfma_f32_16x16x32_f16(fa0.h, bf.h, acc[0][nt], 0, 0, 0); \
        acc[1][nt] = __builtin_amdgcn_mfma_f32_16x16x32_f16(fa1.h, bf.h, acc[1][nt], 0, 0, 0); \
      }
    mg2(Y00[0], fa0.u[0], fa0.u[1]); mg2(Y00[1], fa0.u[2], fa0.u[3]);
    mg2(Y10[0], fa1.u[0], fa1.u[1]); mg2(Y10[1], fa1.u[2], fa1.u[3]);
    MFMA8S(0)
    mg2(Y00[2], fa0.u[0], fa0.u[1]); mg2(Y00[3], fa0.u[2], fa0.u[3]);
    mg2(Y10[2], fa1.u[0], fa1.u[1]); mg2(Y10[3], fa1.u[2], fa1.u[3]);
    Y00 = *(const u32x4*)n0;
    Y10 = *(const u32x4*)n1;
    MFMA8S(1)
    mg2(Y01[0], fa0.u[0], fa0.u[1]); mg2(Y01[1], fa0.u[2], fa0.u[3]);
    mg2(Y11[0], fa1.u[0], fa1.u[1]); mg2(Y11[1], fa1.u[2], fa1.u[3]);
    MFMA8S(2)
    mg2(Y01[2], fa0.u[0], fa0.u[1]); mg2(Y01[3], fa0.u[2], fa0.u[3]);
    mg2(Y11[2], fa1.u[0], fa1.u[1]); mg2(Y11[3], fa1.u[2], fa1.u[3]);
    Y01 = *(const u32x4*)(n0 + 16);
    Y11 = *(const u32x4*)(n1 + 16);
    MFMA8S(3)
    #undef MFMA8S
    #pragma unroll
    for (int mt = 0; mt < 2; ++mt) {
      #pragma unroll
      for (int r = 0; r < 4; ++r) {
        float sum = 0.f;
        #pragma unroll
        for (int nt = 0; nt < 8; ++nt) {
          float h2 = fmaxf(acc[mt][nt][r] + b2r[nt], 0.f);
          sum += h2 * w3r[nt];
        }
        sum += __shfl_xor(sum, 1, 64);
        sum += __shfl_xor(sum, 2, 64);
        sum += __shfl_xor(sum, 4, 64);
        sum += __shfl_xor(sum, 8, 64);
        if (lm == 0) out[ebase + mt*16 + lg*4 + r] = sum + b3v;
      }
    }
    if (!has_next) break;
    tile = next;
    ebase = neb;
  }
}

// ---------------- kernel 4b: fallback gather MFMA pass (round-9) ------
__global__ __launch_bounds__(256) void k_edge(
    const int* __restrict__ ei, const unsigned char* __restrict__ U1,
    const unsigned char* __restrict__ U2, const unsigned short* __restrict__ W2t,
    const float* __restrict__ b2p, const float* __restrict__ W3,
    const float* __restrict__ b3, float* __restrict__ out,
    int E, int ntiles) {
  __shared__ u32x4 w2l[2048];
  const int t = threadIdx.x;
  for (int cchunk = t; cchunk < 2048; cchunk += 256) {
    int n = cchunk >> 4;
    int koff = (cchunk & 15) << 4;
    int swz = koff ^ ((n & 7) << 4);
    w2l[n*16 + (swz >> 4)] =
        *(const u32x4*)((const char*)W2t + (size_t)n*256 + koff);
  }
  __syncthreads();
  const int w = t >> 6, l = t & 63;
  const int lm = l & 15, lg = l >> 4;
  const int lo32 = lg * 32;
  float b2r[8], w3r[8];
  #pragma unroll
  for (int nt = 0; nt < 8; ++nt) {
    b2r[nt] = b2p[nt*16 + lm];
    w3r[nt] = W3[nt*16 + lm];
  }
  const float b3v = *b3;
  const int stride = gridDim.x;
  int tile = blockIdx.x;
  if (tile >= ntiles) return;
  int ebase = tile*128 + w*32;
  u32x4 A00, A01, B00, B01, A10, A11, B10, B11;
  {
    int src0 = ei[ebase + lm],     src1 = ei[ebase + 16 + lm];
    int dst0 = ei[E + ebase + lm], dst1 = ei[E + ebase + 16 + lm];
    A00 = *(const u32x4*)(U1 + (size_t)src0*128 + lo32);
    A01 = *(const u32x4*)(U1 + (size_t)src0*128 + lo32 + 16);
    B00 = *(const u32x4*)(U2 + (size_t)dst0*128 + lo32);
    B01 = *(const u32x4*)(U2 + (size_t)dst0*128 + lo32 + 16);
    A10 = *(const u32x4*)(U1 + (size_t)src1*128 + lo32);
    A11 = *(const u32x4*)(U1 + (size_t)src1*128 + lo32 + 16);
    B10 = *(const u32x4*)(U2 + (size_t)dst1*128 + lo32);
    B11 = *(const u32x4*)(U2 + (size_t)dst1*128 + lo32 + 16);
  }
  while (true) {
    const int next = tile + stride;
    const bool has_next = next < ntiles;
    const int pref = has_next ? next : tile;
    const int neb = pref*128 + w*32;
    int nsrc0 = ei[neb + lm],     nsrc1 = ei[neb + 16 + lm];
    int ndst0 = ei[E + neb + lm], ndst1 = ei[E + neb + 16 + lm];
    f32x4 acc[2][8];
    #pragma unroll
    for (int mt = 0; mt < 2; ++mt)
      #pragma unroll
      for (int nt = 0; nt < 8; ++nt) {
        f32x4 zed = {0.f, 0.f, 0.f, 0.f};
        acc[mt][nt] = zed;
      }
    Frag fa0, fa1;
    #define MFMA8(S)                                                        \
      _Pragma("unroll")                                                     \
      for (int nt = 0; nt < 8; ++nt) {                                      \
        int idx16 = (nt*16 + lm)*16 + (((S)*4 + lg) ^ (lm & 7));            \
        Frag bf; bf.q = w2l[idx16];                                         \
        acc[0][nt] = __builtin_amdgcn_mfma_f32_16x16x32_f16(fa0.h, bf.h, acc[0][nt], 0, 0, 0); \
        acc[1][nt] = __builtin_amdgcn_mfma_f32_16x16x32_f16(fa1.h, bf.h, acc[1][nt], 0, 0, 0); \
      }
    dec4f(A00[0], B00[0], fa0.u[0], fa0.u[1]); dec4f(A00[1], B00[1], fa0.u[2], fa0.u[3]);
    dec4f(A10[0], B10[0], fa1.u[0], fa1.u[1]); dec4f(A10[1], B10[1], fa1.u[2], fa1.u[3]);
    MFMA8(0)
    dec4f(A00[2], B00[2], fa0.u[0], fa0.u[1]); dec4f(A00[3], B00[3], fa0.u[2], fa0.u[3]);
    dec4f(A10[2], B10[2], fa1.u[0], fa1.u[1]); dec4f(A10[3], B10[3], fa1.u[2], fa1.u[3]);
    A00 = *(const u32x4*)(U1 + (size_t)nsrc0*128 + lo32);
    B00 = *(const u32x4*)(U2 + (size_t)ndst0*128 + lo32);
    A10 = *(const u32x4*)(U1 + (size_t)nsrc1*128 + lo32);
    B10 = *(const u32x4*)(U2 + (size_t)ndst1*128 + lo32);
    MFMA8(1)
    dec4f(A01[0], B01[0], fa0.u[0], fa0.u[1]); dec4f(A01[1], B01[1], fa0.u[2], fa0.u[3]);
    dec4f(A11[0], B11[0], fa1.u[0], fa1.u[1]); dec4f(A11[1], B11[1], fa1.u[2], fa1.u[3]);
    MFMA8(2)
    dec4f(A01[2], B01[2], fa0.u[0], fa0.u[1]); dec4f(A01[3], B01[3], fa0.u[2], fa0.u[3]);
    dec4f(A11[2], B11[2], fa1.u[0], fa1.u[1]); dec4f(A11[3], B11[3], fa1.u[2], fa1.u[3]);
    A01 = *(const u32x4*)(U1 + (size_t)nsrc0*128 + lo32 + 16);
    B01 = *(const u32x4*)(U2 + (size_t)ndst0*128 + lo32 + 16);
    A11 = *(const u32x4*)(U1 + (size_t)nsrc1*128 + lo32 + 16);
    B11 = *(const u32x4*)(U2 + (size_t)ndst1*128 + lo32 + 16);
    MFMA8(3)
    #undef MFMA8
    #pragma unroll
    for (int mt = 0; mt < 2; ++mt) {
      #pragma unroll
      for (int r = 0; r < 4; ++r) {
        float sum = 0.f;
        #pragma unroll
        for (int nt = 0; nt < 8; ++nt) {
          float h2 = fmaxf(acc[mt][nt][r] + b2r[nt], 0.f);
          sum += h2 * w3r[nt];
        }
        sum += __shfl_xor(sum, 1, 64);
        sum += __shfl_xor(sum, 2, 64);
        sum += __shfl_xor(sum, 4, 64);
        sum += __shfl_xor(sum, 8, 64);
        if (lm == 0) out[ebase + mt*16 + lg*4 + r] = sum + b3v;
      }
    }
    if (!has_next) break;
    tile = next;
    ebase = neb;
  }
}

extern "C" void kernel_launch(void* const* d_in, const int* in_sizes, int n_in,
                              void* d_out, int out_size, void* d_ws, size_t ws_size,
                              hipStream_t stream) {
  const float* z     = (const float*)d_in[0];
  const int*   ei    = (const int*)d_in[1];
  const float* c     = (const float*)d_in[2];
  const float* W1    = (const float*)d_in[3];
  const float* b1    = (const float*)d_in[4];
  const float* gamma = (const float*)d_in[5];
  const float* beta  = (const float*)d_in[6];
  const float* W2    = (const float*)d_in[7];
  const float* b2    = (const float*)d_in[8];
  const float* W3    = (const float*)d_in[9];
  const float* b3    = (const float*)d_in[10];
  float* out = (float*)d_out;

  const int n_nodes = in_sizes[0] / 64;   // 50000
  const int E       = in_sizes[1] / 2;    // 1600000
  const int NB2 = 1024;

  char* ws = (char*)d_ws;
  const size_t nb128 = (size_t)n_nodes * 128;   // 6.4 MB per table
  unsigned char* U1 = (unsigned char*)ws;
  unsigned char* U2 = U1 + nb128;
  char* p = (char*)(U2 + nb128);
  int* partial        = (int*)p;                 p += (size_t)NB2 * 256 * 4;
  unsigned short* W2t = (unsigned short*)p;      p += 32768;
  float* b2p          = (float*)p;               p += 512;
  float* b2ps         = (float*)p;               p += 512;
  unsigned* gmax1     = (unsigned*)p;            p += 512;
  unsigned* gmax2     = (unsigned*)p;            p += 512;
  float* delta8       = (float*)p;               p += 512;
  float* dinv         = (float*)p;               p += 512;
  unsigned char* H8   = (unsigned char*)p;
  const size_t need   = (size_t)(p - ws) + (size_t)E * 128;   // ~219 MB
  const bool use_h8   = (ws_size >= need);

  hipMemsetAsync(gmax1, 0, 1024, stream);
  const int npb = (n_nodes + 127) / 128;
  k_nodeproj<0><<<npb, 256, 0, stream>>>(z, c, W1, b1, dinv, gmax1, gmax2,
                                         U1, U2, n_nodes);
  k_delta<<<1, 128, 0, stream>>>(gmax1, gmax2, delta8, dinv);
  k_nodeproj<1><<<npb, 256, 0, stream>>>(z, c, W1, b1, dinv, gmax1, gmax2,
                                         U1, U2, n_nodes);
  if (use_h8)
    k_stats<1><<<NB2, 512, 0, stream>>>(ei, U1, U2, partial, H8, E, E/16);
  else
    k_stats<0><<<NB2, 512, 0, stream>>>(ei, U1, U2, partial, H8, E, E/16);
  k_finalize<<<1, 1024, 0, stream>>>(partial, NB2, gamma, beta, W2, b2, delta8,
                                     W2t, b2p, b2ps, 1.0 / (double)E);
  if (use_h8)
    k_edge_h8<<<1024, 256, 0, stream>>>(H8, W2t, b2ps, W3, b3, out, E/128);
  else
    k_edge<<<1024, 256, 0, stream>>>(ei, U1, U2, W2t, b2p, W3, b3, out,
                                     E, E/128);
}

// Round 12
// 422.036 us; speedup vs baseline: 2.9469x; 1.0144x over previous
//
#include <hip/hip_runtime.h>
#include <stdint.h>

typedef _Float16 f16x8 __attribute__((ext_vector_type(8)));
typedef float    f32x4 __attribute__((ext_vector_type(4)));
typedef unsigned u32x4 __attribute__((ext_vector_type(4)));

union Frag { u32x4 q; f16x8 h; unsigned u[4]; };

static __device__ __forceinline__ unsigned short f2h(float f) {
  _Float16 h = (_Float16)f;
  return __builtin_bit_cast(unsigned short, h);
}
static __device__ __forceinline__ unsigned packhf(float lo, float hi) {
  _Float16 a = (_Float16)lo, b = (_Float16)hi;
  unsigned short x = __builtin_bit_cast(unsigned short, a);
  unsigned short y = __builtin_bit_cast(unsigned short, b);
  return (unsigned)x | ((unsigned)y << 16);
}

// u8 decode: bytes are q+128; h = max(qa+qb-256, 0), int in [0,254]
static __device__ __forceinline__ void dec4i(unsigned a, unsigned b, int* h) {
  unsigned lo = (a & 0x00FF00FFu) + (b & 0x00FF00FFu);
  unsigned hi = ((a >> 8) & 0x00FF00FFu) + ((b >> 8) & 0x00FF00FFu);
  int t0 = (int)(lo & 0xFFFFu) - 256;
  int t1 = (int)(hi & 0xFFFFu) - 256;
  int t2 = (int)(lo >> 16) - 256;
  int t3 = (int)(hi >> 16) - 256;
  h[0] = t0 > 0 ? t0 : 0; h[1] = t1 > 0 ? t1 : 0;
  h[2] = t2 > 0 ? t2 : 0; h[3] = t3 > 0 ? t3 : 0;
}
static __device__ __forceinline__ void dec4f(unsigned a, unsigned b,
                                            unsigned& w0, unsigned& w1) {
  int h[4]; dec4i(a, b, h);
  w0 = packhf((float)h[0], (float)h[1]);
  w1 = packhf((float)h[2], (float)h[3]);
}
// magic decode for H8 stream: u32 bytes (h_k0,h_k2,h_k1,h_k3) -> two f16 pairs
// holding 1024+h exactly (offset folded into b2ps).
static __device__ __forceinline__ void mg2(unsigned y, unsigned& w0, unsigned& w1) {
  w0 = (y & 0x00FF00FFu) + 0x64006400u;
  w1 = ((y >> 8) & 0x00FF00FFu) + 0x64006400u;
}

// ---------------- kernel 1: per-node projections (feature-per-thread) --
// STORE=0: track per-feature max -> gmax. STORE=1: quantize u8 (scale from
// gmax computed locally, identical expression to old k_delta).
template<int STORE>
__global__ __launch_bounds__(256) void k_nodeproj(
    const float* __restrict__ z, const float* __restrict__ c,
    const float* __restrict__ W1, const float* __restrict__ b1,
    unsigned* __restrict__ gmax1, unsigned* __restrict__ gmax2,
    unsigned char* __restrict__ U1, unsigned char* __restrict__ U2,
    int n_nodes) {
  __shared__ float zl[128 * 64];   // 32 KB
  const int t = threadIdx.x;
  const int j = t & 127;           // true feature
  const int pj = ((j >> 3) & 3) * 32 + (j >> 5) * 8 + (j & 7);  // permuted byte
  const int half = t >> 7;
  const int nb = blockIdx.x * 128;
  {
    const float* zsrc = z + (size_t)nb * 64;
    const int limit = (n_nodes - nb) * 64;
    for (int i = t; i < 2048; i += 256) {
      f32x4 v = {0.f, 0.f, 0.f, 0.f};
      if (i * 4 + 3 < limit) {
        v = *(const f32x4*)(zsrc + i * 4);
      } else {
        #pragma unroll
        for (int q = 0; q < 4; ++q) if (i * 4 + q < limit) v[q] = zsrc[i * 4 + q];
      }
      *(f32x4*)(zl + i * 4) = v;
    }
  }
  float kvj = b1[j];
  #pragma unroll
  for (int q = 0; q < 4; ++q) kvj += c[q] * W1[(128 + q) * 128 + j];
  float dij = 0.f;
  if (STORE) {
    float m = fmaxf(fmaxf(__uint_as_float(gmax1[j]), __uint_as_float(gmax2[j])),
                    1e-20f);
    dij = 127.0f / m;
  }
  __syncthreads();

  float wreg[64];
  #pragma unroll
  for (int d = 0; d < 64; ++d) wreg[d] = W1[d * 128 + j];
  float mx = 0.f;
  for (int i = 0; i < 64; ++i) {
    const int n = i * 2 + half;
    const int gn = nb + n;
    float acc = kvj;
    #pragma unroll
    for (int d4 = 0; d4 < 16; ++d4) {
      f32x4 zz = *(const f32x4*)(zl + n * 64 + d4 * 4);
      acc += zz[0]*wreg[d4*4+0] + zz[1]*wreg[d4*4+1]
           + zz[2]*wreg[d4*4+2] + zz[3]*wreg[d4*4+3];
    }
    if (STORE) {
      int q8 = (int)rintf(acc * dij);
      q8 = q8 > 127 ? 127 : (q8 < -127 ? -127 : q8);
      if (gn < n_nodes) U1[(size_t)gn * 128 + pj] = (unsigned char)(q8 + 128);
    } else if (gn < n_nodes) {
      mx = fmaxf(mx, fabsf(acc));
    }
  }
  if (!STORE) atomicMax(&gmax1[j], __float_as_uint(mx));
  #pragma unroll
  for (int d = 0; d < 64; ++d) wreg[d] = W1[(64 + d) * 128 + j];
  mx = 0.f;
  for (int i = 0; i < 64; ++i) {
    const int n = i * 2 + half;
    const int gn = nb + n;
    float acc = 0.f;
    #pragma unroll
    for (int d4 = 0; d4 < 16; ++d4) {
      f32x4 zz = *(const f32x4*)(zl + n * 64 + d4 * 4);
      acc += zz[0]*wreg[d4*4+0] + zz[1]*wreg[d4*4+1]
           + zz[2]*wreg[d4*4+2] + zz[3]*wreg[d4*4+3];
    }
    if (STORE) {
      int q8 = (int)rintf(acc * dij);
      q8 = q8 > 127 ? 127 : (q8 < -127 ? -127 : q8);
      if (gn < n_nodes) U2[(size_t)gn * 128 + pj] = (unsigned char)(q8 + 128);
    } else if (gn < n_nodes) {
      mx = fmaxf(mx, fabsf(acc));
    }
  }
  if (!STORE) atomicMax(&gmax2[j], __float_as_uint(mx));
}

// ---------------- kernel 2: BN stats, 2-deep gather pipeline ----------
// Sa consumed while Sb's 4 gathers fly a full iteration; indices prefetched
// one iteration further ahead. WH8: materialize h1 rows (reordered bytes).
template<int WH8>
__global__ __launch_bounds__(512) void k_stats(
    const int* __restrict__ ei, const unsigned char* __restrict__ U1,
    const unsigned char* __restrict__ U2, int* __restrict__ partial,
    unsigned char* __restrict__ H8, int E, int niter16) {
  __shared__ int red[8][256];
  const int t = threadIdx.x;
  const int w = t >> 6, l = t & 63;
  const int es = l >> 3, ch = l & 7;
  int sm[16], sq[16];
  #pragma unroll
  for (int k = 0; k < 16; ++k) { sm[k] = 0; sq[k] = 0; }
  const int nw = gridDim.x * 8;
  int itc = blockIdx.x * 8 + w;
  int itn = itc + nw;
  u32x4 a0c, b0c, a1c, b1c, a0n, b0n, a1n, b1n;
  int ns0 = 0, nd0 = 0, ns1 = 0, nd1 = 0;
  if (itc < niter16) {
    const int e = itc * 16;
    int s0 = ei[e + es],     d0 = ei[E + e + es];
    int s1 = ei[e + 8 + es], d1 = ei[E + e + 8 + es];
    a0c = *(const u32x4*)(U1 + (size_t)s0 * 128 + ch * 16);
    b0c = *(const u32x4*)(U2 + (size_t)d0 * 128 + ch * 16);
    a1c = *(const u32x4*)(U1 + (size_t)s1 * 128 + ch * 16);
    b1c = *(const u32x4*)(U2 + (size_t)d1 * 128 + ch * 16);
  }
  if (itn < niter16) {
    const int e = itn * 16;
    ns0 = ei[e + es];     nd0 = ei[E + e + es];
    ns1 = ei[e + 8 + es]; nd1 = ei[E + e + 8 + es];
  }
  while (itc < niter16) {
    const bool vn = itn < niter16;
    if (vn) {
      // issue next gathers (indices arrived during previous iteration)
      a0n = *(const u32x4*)(U1 + (size_t)ns0 * 128 + ch * 16);
      b0n = *(const u32x4*)(U2 + (size_t)nd0 * 128 + ch * 16);
      a1n = *(const u32x4*)(U1 + (size_t)ns1 * 128 + ch * 16);
      b1n = *(const u32x4*)(U2 + (size_t)nd1 * 128 + ch * 16);
      const int it2 = itn + nw;
      if (it2 < niter16) {
        const int e = it2 * 16;
        ns0 = ei[e + es];     nd0 = ei[E + e + es];
        ns1 = ei[e + 8 + es]; nd1 = ei[E + e + 8 + es];
      }
    }
    const int e16 = itc * 16;
    u32x4 o0, o1;
    #pragma unroll
    for (int qq = 0; qq < 4; ++qq) {
      int h[4];
      dec4i(a0c[qq], b0c[qq], h);
      #pragma unroll
      for (int r = 0; r < 4; ++r) { sm[qq*4+r] += h[r]; sq[qq*4+r] += h[r]*h[r]; }
      if (WH8) o0[qq] = (unsigned)h[0] | ((unsigned)h[2] << 8)
                      | ((unsigned)h[1] << 16) | ((unsigned)h[3] << 24);
      dec4i(a1c[qq], b1c[qq], h);
      #pragma unroll
      for (int r = 0; r < 4; ++r) { sm[qq*4+r] += h[r]; sq[qq*4+r] += h[r]*h[r]; }
      if (WH8) o1[qq] = (unsigned)h[0] | ((unsigned)h[2] << 8)
                      | ((unsigned)h[1] << 16) | ((unsigned)h[3] << 24);
    }
    if (WH8) {
      *(u32x4*)(H8 + (size_t)(e16 + es) * 128 + ch * 16)     = o0;
      *(u32x4*)(H8 + (size_t)(e16 + 8 + es) * 128 + ch * 16) = o1;
    }
    if (!vn) break;
    a0c = a0n; b0c = b0n; a1c = a1n; b1c = b1n;
    itc = itn; itn += nw;
  }
  #pragma unroll
  for (int k = 0; k < 16; ++k) {
    sm[k] += __shfl_xor(sm[k], 8, 64);
    sm[k] += __shfl_xor(sm[k], 16, 64);
    sm[k] += __shfl_xor(sm[k], 32, 64);
    sq[k] += __shfl_xor(sq[k], 8, 64);
    sq[k] += __shfl_xor(sq[k], 16, 64);
    sq[k] += __shfl_xor(sq[k], 32, 64);
  }
  if (es == 0) {
    #pragma unroll
    for (int k = 0; k < 16; ++k) {
      int f = ((ch & 1) * 2 + (k >> 3)) * 32 + (ch >> 1) * 8 + (k & 7);
      red[w][f]       = sm[k];
      red[w][128 + f] = sq[k];
    }
  }
  __syncthreads();
  if (t < 256) {
    int s = 0;
    #pragma unroll
    for (int ww = 0; ww < 8; ++ww) s += red[ww][t];
    partial[(size_t)blockIdx.x * 256 + t] = s;
  }
}

// ---------------- kernel 3: finalize BN + fold scale into W2 ----------
__global__ __launch_bounds__(1024) void k_finalize(
    const int* __restrict__ partial, int nb,
    const float* __restrict__ gamma, const float* __restrict__ beta,
    const float* __restrict__ W2, const float* __restrict__ b2,
    const unsigned* __restrict__ gmax1, const unsigned* __restrict__ gmax2,
    unsigned short* __restrict__ W2t, float* __restrict__ b2p,
    float* __restrict__ b2ps, double Einv) {
  __shared__ double redd[4][256];
  __shared__ double stat[256];
  __shared__ float ajd[128], bbj[128];
  __shared__ float bacc[8][128];
  const int t = threadIdx.x;
  const int slot = t & 255, g = t >> 8;
  double s = 0.0;
  for (int b = g; b < nb; b += 4) s += (double)partial[(size_t)b * 256 + slot];
  redd[g][slot] = s;
  __syncthreads();
  if (t < 256) stat[t] = redd[0][t] + redd[1][t] + redd[2][t] + redd[3][t];
  __syncthreads();
  if (t < 128) {
    float m = fmaxf(fmaxf(__uint_as_float(gmax1[t]), __uint_as_float(gmax2[t])),
                    1e-20f);
    double d8 = (double)(m * (1.0f / 127.0f));
    double mean = d8 * stat[t] * Einv;
    double ex2  = d8 * d8 * stat[128 + t] * Einv;
    double var  = ex2 - mean * mean;
    float a = (float)((double)gamma[t] / sqrt(var + 1e-5));
    ajd[t] = a * (float)d8;
    bbj[t] = beta[t] - (float)mean * a;
  }
  __syncthreads();
  for (int cidx = t; cidx < 16384; cidx += 1024) {
    int i = cidx >> 7;
    int j = cidx & 127;
    W2t[j * 128 + i] = f2h(ajd[i] * W2[cidx]);
  }
  {
    const int col = t & 127, g2 = t >> 7;
    float acc = 0.f;
    #pragma unroll
    for (int q = 0; q < 16; ++q) {
      int i = g2 * 16 + q;
      acc += bbj[i] * W2[i * 128 + col];
    }
    bacc[g2][col] = acc;
  }
  __syncthreads();
  if (t < 128) {
    float a = b2[t];
    #pragma unroll
    for (int g3 = 0; g3 < 8; ++g3) a += bacc[g3][t];
    b2p[t] = a;
    float c = 0.f;
    for (int i = 0; i < 128; ++i)
      c += (float)((_Float16)(ajd[i] * W2[i * 128 + t]));
    b2ps[t] = a - 1024.0f * c;
  }
}

// ---------------- kernel 4a: streaming MFMA over H8, double-buffered ---
__global__ __launch_bounds__(256) void k_edge_h8(
    const unsigned char* __restrict__ H8, const unsigned short* __restrict__ W2t,
    const float* __restrict__ b2ps, const float* __restrict__ W3,
    const float* __restrict__ b3, float* __restrict__ out, int ntiles) {
  __shared__ u32x4 w2l[2048];
  const int t = threadIdx.x;
  for (int cchunk = t; cchunk < 2048; cchunk += 256) {
    int n = cchunk >> 4;
    int koff = (cchunk & 15) << 4;
    int swz = koff ^ ((n & 7) << 4);
    w2l[n*16 + (swz >> 4)] =
        *(const u32x4*)((const char*)W2t + (size_t)n*256 + koff);
  }
  __syncthreads();
  const int w = t >> 6, l = t & 63;
  const int lm = l & 15, lg = l >> 4;
  const int lo32 = lg * 32;
  float b2r[8], w3r[8];
  #pragma unroll
  for (int nt = 0; nt < 8; ++nt) {
    b2r[nt] = b2ps[nt*16 + lm];
    w3r[nt] = W3[nt*16 + lm];
  }
  const float b3v = *b3;
  const int stride = gridDim.x;
  int tile = blockIdx.x;
  if (tile >= ntiles) return;
  int ebase = tile*128 + w*32;
  u32x4 Ya00, Ya01, Ya10, Ya11, Yb00, Yb01, Yb10, Yb11;
  {
    const unsigned char* r0 = H8 + (size_t)(ebase + lm) * 128 + lo32;
    const unsigned char* r1 = H8 + (size_t)(ebase + 16 + lm) * 128 + lo32;
    Ya00 = *(const u32x4*)r0;  Ya01 = *(const u32x4*)(r0 + 16);
    Ya10 = *(const u32x4*)r1;  Ya11 = *(const u32x4*)(r1 + 16);
  }
  while (true) {
    const int next = tile + stride;
    const bool has_next = next < ntiles;
    const int pref = has_next ? next : tile;
    const int neb = pref*128 + w*32;
    {
      // issue ALL next-tile loads before any compute: a full tile of slack
      const unsigned char* n0 = H8 + (size_t)(neb + lm) * 128 + lo32;
      const unsigned char* n1 = H8 + (size_t)(neb + 16 + lm) * 128 + lo32;
      Yb00 = *(const u32x4*)n0;  Yb01 = *(const u32x4*)(n0 + 16);
      Yb10 = *(const u32x4*)n1;  Yb11 = *(const u32x4*)(n1 + 16);
    }
    f32x4 acc[2][8];
    #pragma unroll
    for (int mt = 0; mt < 2; ++mt)
      #pragma unroll
      for (int nt = 0; nt < 8; ++nt) {
        f32x4 zed = {0.f, 0.f, 0.f, 0.f};
        acc[mt][nt] = zed;
      }
    Frag fa0, fa1;
    #define MFMA8S(S)                                                       \
      _Pragma("unroll")                                                     \
      for (int nt = 0; nt < 8; ++nt) {                                      \
        int idx16 = (nt*16 + lm)*16 + (((S)*4 + lg) ^ (lm & 7));            \
        Frag bf; bf.q = w2l[idx16];                                         \
        acc[0][nt] = __builtin_amdgcn_mfma_f32_16x16x32_f16(fa0.h, bf.h, acc[0][nt], 0, 0, 0); \
        acc[1][nt] = __builtin_amdgcn_mfma_f32_16x16x32_f16(fa1.h, bf.h, acc[1][nt], 0, 0, 0); \
      }
    mg2(Ya00[0], fa0.u[0], fa0.u[1]); mg2(Ya00[1], fa0.u[2], fa0.u[3]);
    mg2(Ya10[0], fa1.u[0], fa1.u[1]); mg2(Ya10[1], fa1.u[2], fa1.u[3]);
    MFMA8S(0)
    mg2(Ya00[2], fa0.u[0], fa0.u[1]); mg2(Ya00[3], fa0.u[2], fa0.u[3]);
    mg2(Ya10[2], fa1.u[0], fa1.u[1]); mg2(Ya10[3], fa1.u[2], fa1.u[3]);
    MFMA8S(1)
    mg2(Ya01[0], fa0.u[0], fa0.u[1]); mg2(Ya01[1], fa0.u[2], fa0.u[3]);
    mg2(Ya11[0], fa1.u[0], fa1.u[1]); mg2(Ya11[1], fa1.u[2], fa1.u[3]);
    MFMA8S(2)
    mg2(Ya01[2], fa0.u[0], fa0.u[1]); mg2(Ya01[3], fa0.u[2], fa0.u[3]);
    mg2(Ya11[2], fa1.u[0], fa1.u[1]); mg2(Ya11[3], fa1.u[2], fa1.u[3]);
    MFMA8S(3)
    #undef MFMA8S
    #pragma unroll
    for (int mt = 0; mt < 2; ++mt) {
      #pragma unroll
      for (int r = 0; r < 4; ++r) {
        float sum = 0.f;
        #pragma unroll
        for (int nt = 0; nt < 8; ++nt) {
          float h2 = fmaxf(acc[mt][nt][r] + b2r[nt], 0.f);
          sum += h2 * w3r[nt];
        }
        sum += __shfl_xor(sum, 1, 64);
        sum += __shfl_xor(sum, 2, 64);
        sum += __shfl_xor(sum, 4, 64);
        sum += __shfl_xor(sum, 8, 64);
        if (lm == 0) out[ebase + mt*16 + lg*4 + r] = sum + b3v;
      }
    }
    if (!has_next) break;
    tile = next;
    ebase = neb;
    Ya00 = Yb00; Ya01 = Yb01; Ya10 = Yb10; Ya11 = Yb11;
  }
}

// ---------------- kernel 4b: fallback gather MFMA pass ----------------
__global__ __launch_bounds__(256) void k_edge(
    const int* __restrict__ ei, const unsigned char* __restrict__ U1,
    const unsigned char* __restrict__ U2, const unsigned short* __restrict__ W2t,
    const float* __restrict__ b2p, const float* __restrict__ W3,
    const float* __restrict__ b3, float* __restrict__ out,
    int E, int ntiles) {
  __shared__ u32x4 w2l[2048];
  const int t = threadIdx.x;
  for (int cchunk = t; cchunk < 2048; cchunk += 256) {
    int n = cchunk >> 4;
    int koff = (cchunk & 15) << 4;
    int swz = koff ^ ((n & 7) << 4);
    w2l[n*16 + (swz >> 4)] =
        *(const u32x4*)((const char*)W2t + (size_t)n*256 + koff);
  }
  __syncthreads();
  const int w = t >> 6, l = t & 63;
  const int lm = l & 15, lg = l >> 4;
  const int lo32 = lg * 32;
  float b2r[8], w3r[8];
  #pragma unroll
  for (int nt = 0; nt < 8; ++nt) {
    b2r[nt] = b2p[nt*16 + lm];
    w3r[nt] = W3[nt*16 + lm];
  }
  const float b3v = *b3;
  const int stride = gridDim.x;
  int tile = blockIdx.x;
  if (tile >= ntiles) return;
  int ebase = tile*128 + w*32;
  u32x4 A00, A01, B00, B01, A10, A11, B10, B11;
  {
    int src0 = ei[ebase + lm],     src1 = ei[ebase + 16 + lm];
    int dst0 = ei[E + ebase + lm], dst1 = ei[E + ebase + 16 + lm];
    A00 = *(const u32x4*)(U1 + (size_t)src0*128 + lo32);
    A01 = *(const u32x4*)(U1 + (size_t)src0*128 + lo32 + 16);
    B00 = *(const u32x4*)(U2 + (size_t)dst0*128 + lo32);
    B01 = *(const u32x4*)(U2 + (size_t)dst0*128 + lo32 + 16);
    A10 = *(const u32x4*)(U1 + (size_t)src1*128 + lo32);
    A11 = *(const u32x4*)(U1 + (size_t)src1*128 + lo32 + 16);
    B10 = *(const u32x4*)(U2 + (size_t)dst1*128 + lo32);
    B11 = *(const u32x4*)(U2 + (size_t)dst1*128 + lo32 + 16);
  }
  while (true) {
    const int next = tile + stride;
    const bool has_next = next < ntiles;
    const int pref = has_next ? next : tile;
    const int neb = pref*128 + w*32;
    int nsrc0 = ei[neb + lm],     nsrc1 = ei[neb + 16 + lm];
    int ndst0 = ei[E + neb + lm], ndst1 = ei[E + neb + 16 + lm];
    f32x4 acc[2][8];
    #pragma unroll
    for (int mt = 0; mt < 2; ++mt)
      #pragma unroll
      for (int nt = 0; nt < 8; ++nt) {
        f32x4 zed = {0.f, 0.f, 0.f, 0.f};
        acc[mt][nt] = zed;
      }
    Frag fa0, fa1;
    #define MFMA8(S)                                                        \
      _Pragma("unroll")                                                     \
      for (int nt = 0; nt < 8; ++nt) {                                      \
        int idx16 = (nt*16 + lm)*16 + (((S)*4 + lg) ^ (lm & 7));            \
        Frag bf; bf.q = w2l[idx16];                                         \
        acc[0][nt] = __builtin_amdgcn_mfma_f32_16x16x32_f16(fa0.h, bf.h, acc[0][nt], 0, 0, 0); \
        acc[1][nt] = __builtin_amdgcn_mfma_f32_16x16x32_f16(fa1.h, bf.h, acc[1][nt], 0, 0, 0); \
      }
    dec4f(A00[0], B00[0], fa0.u[0], fa0.u[1]); dec4f(A00[1], B00[1], fa0.u[2], fa0.u[3]);
    dec4f(A10[0], B10[0], fa1.u[0], fa1.u[1]); dec4f(A10[1], B10[1], fa1.u[2], fa1.u[3]);
    MFMA8(0)
    dec4f(A00[2], B00[2], fa0.u[0], fa0.u[1]); dec4f(A00[3], B00[3], fa0.u[2], fa0.u[3]);
    dec4f(A10[2], B10[2], fa1.u[0], fa1.u[1]); dec4f(A10[3], B10[3], fa1.u[2], fa1.u[3]);
    A00 = *(const u32x4*)(U1 + (size_t)nsrc0*128 + lo32);
    B00 = *(const u32x4*)(U2 + (size_t)ndst0*128 + lo32);
    A10 = *(const u32x4*)(U1 + (size_t)nsrc1*128 + lo32);
    B10 = *(const u32x4*)(U2 + (size_t)ndst1*128 + lo32);
    MFMA8(1)
    dec4f(A01[0], B01[0], fa0.u[0], fa0.u[1]); dec4f(A01[1], B01[1], fa0.u[2], fa0.u[3]);
    dec4f(A11[0], B11[0], fa1.u[0], fa1.u[1]); dec4f(A11[1], B11[1], fa1.u[2], fa1.u[3]);
    MFMA8(2)
    dec4f(A01[2], B01[2], fa0.u[0], fa0.u[1]); dec4f(A01[3], B01[3], fa0.u[2], fa0.u[3]);
    dec4f(A11[2], B11[2], fa1.u[0], fa1.u[1]); dec4f(A11[3], B11[3], fa1.u[2], fa1.u[3]);
    A01 = *(const u32x4*)(U1 + (size_t)nsrc0*128 + lo32 + 16);
    B01 = *(const u32x4*)(U2 + (size_t)ndst0*128 + lo32 + 16);
    A11 = *(const u32x4*)(U1 + (size_t)nsrc1*128 + lo32 + 16);
    B11 = *(const u32x4*)(U2 + (size_t)ndst1*128 + lo32 + 16);
    MFMA8(3)
    #undef MFMA8
    #pragma unroll
    for (int mt = 0; mt < 2; ++mt) {
      #pragma unroll
      for (int r = 0; r < 4; ++r) {
        float sum = 0.f;
        #pragma unroll
        for (int nt = 0; nt < 8; ++nt) {
          float h2 = fmaxf(acc[mt][nt][r] + b2r[nt], 0.f);
          sum += h2 * w3r[nt];
        }
        sum += __shfl_xor(sum, 1, 64);
        sum += __shfl_xor(sum, 2, 64);
        sum += __shfl_xor(sum, 4, 64);
        sum += __shfl_xor(sum, 8, 64);
        if (lm == 0) out[ebase + mt*16 + lg*4 + r] = sum + b3v;
      }
    }
    if (!has_next) break;
    tile = next;
    ebase = neb;
  }
}

extern "C" void kernel_launch(void* const* d_in, const int* in_sizes, int n_in,
                              void* d_out, int out_size, void* d_ws, size_t ws_size,
                              hipStream_t stream) {
  const float* z     = (const float*)d_in[0];
  const int*   ei    = (const int*)d_in[1];
  const float* c     = (const float*)d_in[2];
  const float* W1    = (const float*)d_in[3];
  const float* b1    = (const float*)d_in[4];
  const float* gamma = (const float*)d_in[5];
  const float* beta  = (const float*)d_in[6];
  const float* W2    = (const float*)d_in[7];
  const float* b2    = (const float*)d_in[8];
  const float* W3    = (const float*)d_in[9];
  const float* b3    = (const float*)d_in[10];
  float* out = (float*)d_out;

  const int n_nodes = in_sizes[0] / 64;   // 50000
  const int E       = in_sizes[1] / 2;    // 1600000
  const int NB2 = 1024;

  char* ws = (char*)d_ws;
  const size_t nb128 = (size_t)n_nodes * 128;   // 6.4 MB per table
  unsigned char* U1 = (unsigned char*)ws;
  unsigned char* U2 = U1 + nb128;
  char* p = (char*)(U2 + nb128);
  int* partial        = (int*)p;                 p += (size_t)NB2 * 256 * 4;
  unsigned short* W2t = (unsigned short*)p;      p += 32768;
  float* b2p          = (float*)p;               p += 512;
  float* b2ps         = (float*)p;               p += 512;
  unsigned* gmax1     = (unsigned*)p;            p += 512;
  unsigned* gmax2     = (unsigned*)p;            p += 512;
  unsigned char* H8   = (unsigned char*)p;
  const size_t need   = (size_t)(p - ws) + (size_t)E * 128;   // ~219 MB
  const bool use_h8   = (ws_size >= need);

  hipMemsetAsync(gmax1, 0, 1024, stream);
  const int npb = (n_nodes + 127) / 128;
  k_nodeproj<0><<<npb, 256, 0, stream>>>(z, c, W1, b1, gmax1, gmax2,
                                         U1, U2, n_nodes);
  k_nodeproj<1><<<npb, 256, 0, stream>>>(z, c, W1, b1, gmax1, gmax2,
                                         U1, U2, n_nodes);
  if (use_h8)
    k_stats<1><<<NB2, 512, 0, stream>>>(ei, U1, U2, partial, H8, E, E/16);
  else
    k_stats<0><<<NB2, 512, 0, stream>>>(ei, U1, U2, partial, H8, E, E/16);
  k_finalize<<<1, 1024, 0, stream>>>(partial, NB2, gamma, beta, W2, b2,
                                     gmax1, gmax2, W2t, b2p, b2ps,
                                     1.0 / (double)E);
  if (use_h8)
    k_edge_h8<<<1024, 256, 0, stream>>>(H8, W2t, b2ps, W3, b3, out, E/128);
  else
    k_edge<<<1024, 256, 0, stream>>>(ei, U1, U2, W2t, b2p, W3, b3, out,
                                     E, E/128);
}

// Round 16
// 362.359 us; speedup vs baseline: 3.4323x; 1.1647x over previous
//
#include <hip/hip_runtime.h>
#include <stdint.h>

typedef _Float16 f16x8 __attribute__((ext_vector_type(8)));
typedef float    f32x4 __attribute__((ext_vector_type(4)));
typedef unsigned u32x4 __attribute__((ext_vector_type(4)));

union Frag { u32x4 q; f16x8 h; unsigned u[4]; };

static __device__ __forceinline__ unsigned short f2h(float f) {
  _Float16 h = (_Float16)f;
  return __builtin_bit_cast(unsigned short, h);
}
// u8 decode: bytes are q+128; h = max(qa+qb-256, 0), int in [0,254]
static __device__ __forceinline__ void dec4i(unsigned a, unsigned b, int* h) {
  unsigned lo = (a & 0x00FF00FFu) + (b & 0x00FF00FFu);
  unsigned hi = ((a >> 8) & 0x00FF00FFu) + ((b >> 8) & 0x00FF00FFu);
  int t0 = (int)(lo & 0xFFFFu) - 256;
  int t1 = (int)(hi & 0xFFFFu) - 256;
  int t2 = (int)(lo >> 16) - 256;
  int t3 = (int)(hi >> 16) - 256;
  h[0] = t0 > 0 ? t0 : 0; h[1] = t1 > 0 ? t1 : 0;
  h[2] = t2 > 0 ? t2 : 0; h[3] = t3 > 0 ? t3 : 0;
}
// magic decode for H8 stream: u32 bytes (h_k0,h_k2,h_k1,h_k3) -> two f16 pairs
// holding 1024+h exactly (offset folded into b2ps).
static __device__ __forceinline__ void mg2(unsigned y, unsigned& w0, unsigned& w1) {
  w0 = (y & 0x00FF00FFu) + 0x64006400u;
  w1 = ((y >> 8) & 0x00FF00FFu) + 0x64006400u;
}
// DPP quad-perm lane-xor add (VALU pipe, not LDS): xor1=0xB1, xor2=0x4E
// CTRL must be a compile-time constant (builtin requires ICE) -> template.
template<int CTRL>
static __device__ __forceinline__ float dppadd(float s) {
  int v = __builtin_amdgcn_mov_dpp(__builtin_bit_cast(int, s), CTRL, 0xf, 0xf, true);
  return s + __builtin_bit_cast(float, v);
}

// ---------------- kernel 1: per-node projections (feature-per-thread) --
// Single GEMM pass: stores f32 projections Tf1/Tf2 AND per-feature max.
__global__ __launch_bounds__(256) void k_nodeproj(
    const float* __restrict__ z, const float* __restrict__ c,
    const float* __restrict__ W1, const float* __restrict__ b1,
    unsigned* __restrict__ gmax1, unsigned* __restrict__ gmax2,
    float* __restrict__ Tf1, float* __restrict__ Tf2, int n_nodes) {
  __shared__ float zl[128 * 64];   // 32 KB
  const int t = threadIdx.x;
  const int j = t & 127;           // true feature
  const int half = t >> 7;
  const int nb = blockIdx.x * 128;
  {
    const float* zsrc = z + (size_t)nb * 64;
    const int limit = (n_nodes - nb) * 64;
    for (int i = t; i < 2048; i += 256) {
      f32x4 v = {0.f, 0.f, 0.f, 0.f};
      if (i * 4 + 3 < limit) {
        v = *(const f32x4*)(zsrc + i * 4);
      } else {
        #pragma unroll
        for (int q = 0; q < 4; ++q) if (i * 4 + q < limit) v[q] = zsrc[i * 4 + q];
      }
      *(f32x4*)(zl + i * 4) = v;
    }
  }
  float kvj = b1[j];
  #pragma unroll
  for (int q = 0; q < 4; ++q) kvj += c[q] * W1[(128 + q) * 128 + j];
  __syncthreads();

  float wreg[64];
  // ---- half A: T1 (W1 rows 0..63), bias kvj ----
  #pragma unroll
  for (int d = 0; d < 64; ++d) wreg[d] = W1[d * 128 + j];
  float mx = 0.f;
  for (int i = 0; i < 64; ++i) {
    const int n = i * 2 + half;
    const int gn = nb + n;
    float acc = kvj;
    #pragma unroll
    for (int d4 = 0; d4 < 16; ++d4) {
      f32x4 zz = *(const f32x4*)(zl + n * 64 + d4 * 4);
      acc += zz[0]*wreg[d4*4+0] + zz[1]*wreg[d4*4+1]
           + zz[2]*wreg[d4*4+2] + zz[3]*wreg[d4*4+3];
    }
    if (gn < n_nodes) {
      Tf1[(size_t)gn * 128 + j] = acc;
      mx = fmaxf(mx, fabsf(acc));
    }
  }
  atomicMax(&gmax1[j], __float_as_uint(mx));
  // ---- half B: T2 (W1 rows 64..127), no bias ----
  #pragma unroll
  for (int d = 0; d < 64; ++d) wreg[d] = W1[(64 + d) * 128 + j];
  mx = 0.f;
  for (int i = 0; i < 64; ++i) {
    const int n = i * 2 + half;
    const int gn = nb + n;
    float acc = 0.f;
    #pragma unroll
    for (int d4 = 0; d4 < 16; ++d4) {
      f32x4 zz = *(const f32x4*)(zl + n * 64 + d4 * 4);
      acc += zz[0]*wreg[d4*4+0] + zz[1]*wreg[d4*4+1]
           + zz[2]*wreg[d4*4+2] + zz[3]*wreg[d4*4+3];
    }
    if (gn < n_nodes) {
      Tf2[(size_t)gn * 128 + j] = acc;
      mx = fmaxf(mx, fabsf(acc));
    }
  }
  atomicMax(&gmax2[j], __float_as_uint(mx));
}

// ---------------- kernel 1b: streaming quantize Tf -> permuted u8 -----
// Thread: one (table, node, g) sixteenth-row. Bit-identical to the old
// in-GEMM quantize: same f32 acc, same dij expression, same rint/clamp.
__global__ __launch_bounds__(256) void k_quant(
    const float* __restrict__ Tf1, const float* __restrict__ Tf2,
    const unsigned* __restrict__ g1, const unsigned* __restrict__ g2,
    unsigned char* __restrict__ U1, unsigned char* __restrict__ U2,
    int n_nodes) {
  const int tid = blockIdx.x * 256 + threadIdx.x;
  const int tot = n_nodes * 8;
  if (tid >= 2 * tot) return;
  const int table = tid >= tot;
  const int r = tid - table * tot;
  const int node = r >> 3, g = r & 7;
  const float* src = (table ? Tf2 : Tf1) + (size_t)node * 128 + g * 16;
  unsigned char* dst = (table ? U2 : U1) + (size_t)node * 128;
  f32x4 v[4];
  #pragma unroll
  for (int q = 0; q < 4; ++q) v[q] = *(const f32x4*)(src + q * 4);
  #pragma unroll
  for (int b = 0; b < 2; ++b) {
    unsigned w0 = 0, w1 = 0;
    #pragma unroll
    for (int k = 0; k < 8; ++k) {
      const int f = g * 16 + b * 8 + k;
      float m = fmaxf(fmaxf(__uint_as_float(g1[f]), __uint_as_float(g2[f])),
                      1e-20f);
      float dij = 127.0f / m;
      float acc = v[b * 2 + (k >> 2)][k & 3];
      int q8 = (int)rintf(acc * dij);
      q8 = q8 > 127 ? 127 : (q8 < -127 ? -127 : q8);
      unsigned by = (unsigned)(q8 + 128);
      if (k < 4) w0 |= by << (8 * k); else w1 |= by << (8 * (k - 4));
    }
    const int off = (((2 * g + b) & 3) * 32) + ((g >> 1) * 8);
    *(unsigned*)(dst + off)     = w0;
    *(unsigned*)(dst + off + 4) = w1;
  }
}

// ---------------- kernel 2: BN stats, 2-deep gather pipeline ----------
template<int WH8>
__global__ __launch_bounds__(512) void k_stats(
    const int* __restrict__ ei, const unsigned char* __restrict__ U1,
    const unsigned char* __restrict__ U2, int* __restrict__ partial,
    unsigned char* __restrict__ H8, int E, int niter16) {
  __shared__ int red[8][256];
  const int t = threadIdx.x;
  const int w = t >> 6, l = t & 63;
  const int es = l >> 3, ch = l & 7;
  int sm[16], sq[16];
  #pragma unroll
  for (int k = 0; k < 16; ++k) { sm[k] = 0; sq[k] = 0; }
  const int nw = gridDim.x * 8;
  int itc = blockIdx.x * 8 + w;
  int itn = itc + nw;
  u32x4 a0c, b0c, a1c, b1c, a0n, b0n, a1n, b1n;
  int ns0 = 0, nd0 = 0, ns1 = 0, nd1 = 0;
  if (itc < niter16) {
    const int e = itc * 16;
    int s0 = ei[e + es],     d0 = ei[E + e + es];
    int s1 = ei[e + 8 + es], d1 = ei[E + e + 8 + es];
    a0c = *(const u32x4*)(U1 + (size_t)s0 * 128 + ch * 16);
    b0c = *(const u32x4*)(U2 + (size_t)d0 * 128 + ch * 16);
    a1c = *(const u32x4*)(U1 + (size_t)s1 * 128 + ch * 16);
    b1c = *(const u32x4*)(U2 + (size_t)d1 * 128 + ch * 16);
  }
  if (itn < niter16) {
    const int e = itn * 16;
    ns0 = ei[e + es];     nd0 = ei[E + e + es];
    ns1 = ei[e + 8 + es]; nd1 = ei[E + e + 8 + es];
  }
  while (itc < niter16) {
    const bool vn = itn < niter16;
    if (vn) {
      a0n = *(const u32x4*)(U1 + (size_t)ns0 * 128 + ch * 16);
      b0n = *(const u32x4*)(U2 + (size_t)nd0 * 128 + ch * 16);
      a1n = *(const u32x4*)(U1 + (size_t)ns1 * 128 + ch * 16);
      b1n = *(const u32x4*)(U2 + (size_t)nd1 * 128 + ch * 16);
      const int it2 = itn + nw;
      if (it2 < niter16) {
        const int e = it2 * 16;
        ns0 = ei[e + es];     nd0 = ei[E + e + es];
        ns1 = ei[e + 8 + es]; nd1 = ei[E + e + 8 + es];
      }
    }
    const int e16 = itc * 16;
    u32x4 o0, o1;
    #pragma unroll
    for (int qq = 0; qq < 4; ++qq) {
      int h[4];
      dec4i(a0c[qq], b0c[qq], h);
      #pragma unroll
      for (int r = 0; r < 4; ++r) { sm[qq*4+r] += h[r]; sq[qq*4+r] += h[r]*h[r]; }
      if (WH8) o0[qq] = (unsigned)h[0] | ((unsigned)h[2] << 8)
                      | ((unsigned)h[1] << 16) | ((unsigned)h[3] << 24);
      dec4i(a1c[qq], b1c[qq], h);
      #pragma unroll
      for (int r = 0; r < 4; ++r) { sm[qq*4+r] += h[r]; sq[qq*4+r] += h[r]*h[r]; }
      if (WH8) o1[qq] = (unsigned)h[0] | ((unsigned)h[2] << 8)
                      | ((unsigned)h[1] << 16) | ((unsigned)h[3] << 24);
    }
    if (WH8) {
      *(u32x4*)(H8 + (size_t)(e16 + es) * 128 + ch * 16)     = o0;
      *(u32x4*)(H8 + (size_t)(e16 + 8 + es) * 128 + ch * 16) = o1;
    }
    if (!vn) break;
    a0c = a0n; b0c = b0n; a1c = a1n; b1c = b1n;
    itc = itn; itn += nw;
  }
  #pragma unroll
  for (int k = 0; k < 16; ++k) {
    sm[k] += __shfl_xor(sm[k], 8, 64);
    sm[k] += __shfl_xor(sm[k], 16, 64);
    sm[k] += __shfl_xor(sm[k], 32, 64);
    sq[k] += __shfl_xor(sq[k], 8, 64);
    sq[k] += __shfl_xor(sq[k], 16, 64);
    sq[k] += __shfl_xor(sq[k], 32, 64);
  }
  if (es == 0) {
    #pragma unroll
    for (int k = 0; k < 16; ++k) {
      int f = ((ch & 1) * 2 + (k >> 3)) * 32 + (ch >> 1) * 8 + (k & 7);
      red[w][f]       = sm[k];
      red[w][128 + f] = sq[k];
    }
  }
  __syncthreads();
  if (t < 256) {
    int s = 0;
    #pragma unroll
    for (int ww = 0; ww < 8; ++ww) s += red[ww][t];
    partial[(size_t)blockIdx.x * 256 + t] = s;
  }
}

// ---------------- kernel 3: finalize BN + fold scale into W2 ----------
__global__ __launch_bounds__(1024) void k_finalize(
    const int* __restrict__ partial, int nb,
    const float* __restrict__ gamma, const float* __restrict__ beta,
    const float* __restrict__ W2, const float* __restrict__ b2,
    const unsigned* __restrict__ gmax1, const unsigned* __restrict__ gmax2,
    unsigned short* __restrict__ W2t, float* __restrict__ b2p,
    float* __restrict__ b2ps, double Einv) {
  __shared__ double redd[4][256];
  __shared__ double stat[256];
  __shared__ float ajd[128], bbj[128];
  __shared__ float bacc[8][128];
  const int t = threadIdx.x;
  const int slot = t & 255, g = t >> 8;
  double s = 0.0;
  for (int b = g; b < nb; b += 4) s += (double)partial[(size_t)b * 256 + slot];
  redd[g][slot] = s;
  __syncthreads();
  if (t < 256) stat[t] = redd[0][t] + redd[1][t] + redd[2][t] + redd[3][t];
  __syncthreads();
  if (t < 128) {
    float m = fmaxf(fmaxf(__uint_as_float(gmax1[t]), __uint_as_float(gmax2[t])),
                    1e-20f);
    double d8 = (double)(m * (1.0f / 127.0f));
    double mean = d8 * stat[t] * Einv;
    double ex2  = d8 * d8 * stat[128 + t] * Einv;
    double var  = ex2 - mean * mean;
    float a = (float)((double)gamma[t] / sqrt(var + 1e-5));
    ajd[t] = a * (float)d8;
    bbj[t] = beta[t] - (float)mean * a;
  }
  __syncthreads();
  for (int cidx = t; cidx < 16384; cidx += 1024) {
    int i = cidx >> 7;
    int j = cidx & 127;
    W2t[j * 128 + i] = f2h(ajd[i] * W2[cidx]);
  }
  {
    const int col = t & 127, g2 = t >> 7;
    float acc = 0.f;
    #pragma unroll
    for (int q = 0; q < 16; ++q) {
      int i = g2 * 16 + q;
      acc += bbj[i] * W2[i * 128 + col];
    }
    bacc[g2][col] = acc;
  }
  __syncthreads();
  if (t < 128) {
    float a = b2[t];
    #pragma unroll
    for (int g3 = 0; g3 < 8; ++g3) a += bacc[g3][t];
    b2p[t] = a;
    float c = 0.f;
    for (int i = 0; i < 128; ++i)
      c += (float)((_Float16)(ajd[i] * W2[i * 128 + t]));
    b2ps[t] = a - 1024.0f * c;
  }
}

// ---------------- kernel 4a: streaming MFMA over H8, double-buffered ---
__global__ __launch_bounds__(256) void k_edge_h8(
    const unsigned char* __restrict__ H8, const unsigned short* __restrict__ W2t,
    const float* __restrict__ b2ps, const float* __restrict__ W3,
    const float* __restrict__ b3, float* __restrict__ out, int ntiles) {
  __shared__ u32x4 w2l[2048];
  const int t = threadIdx.x;
  for (int cchunk = t; cchunk < 2048; cchunk += 256) {
    int n = cchunk >> 4;
    int koff = (cchunk & 15) << 4;
    int swz = koff ^ ((n & 7) << 4);
    w2l[n*16 + (swz >> 4)] =
        *(const u32x4*)((const char*)W2t + (size_t)n*256 + koff);
  }
  __syncthreads();
  const int w = t >> 6, l = t & 63;
  const int lm = l & 15, lg = l >> 4;
  const int lo32 = lg * 32;
  float b2r[8], w3r[8];
  #pragma unroll
  for (int nt = 0; nt < 8; ++nt) {
    b2r[nt] = b2ps[nt*16 + lm];
    w3r[nt] = W3[nt*16 + lm];
  }
  const float b3v = *b3;
  const int stride = gridDim.x;
  int tile = blockIdx.x;
  if (tile >= ntiles) return;
  int ebase = tile*128 + w*32;
  u32x4 Ya00, Ya01, Ya10, Ya11, Yb00, Yb01, Yb10, Yb11;
  {
    const unsigned char* r0 = H8 + (size_t)(ebase + lm) * 128 + lo32;
    const unsigned char* r1 = H8 + (size_t)(ebase + 16 + lm) * 128 + lo32;
    Ya00 = *(const u32x4*)r0;  Ya01 = *(const u32x4*)(r0 + 16);
    Ya10 = *(const u32x4*)r1;  Ya11 = *(const u32x4*)(r1 + 16);
  }
  while (true) {
    const int next = tile + stride;
    const bool has_next = next < ntiles;
    const int pref = has_next ? next : tile;
    const int neb = pref*128 + w*32;
    {
      const unsigned char* n0 = H8 + (size_t)(neb + lm) * 128 + lo32;
      const unsigned char* n1 = H8 + (size_t)(neb + 16 + lm) * 128 + lo32;
      Yb00 = *(const u32x4*)n0;  Yb01 = *(const u32x4*)(n0 + 16);
      Yb10 = *(const u32x4*)n1;  Yb11 = *(const u32x4*)(n1 + 16);
    }
    f32x4 acc[2][8];
    #pragma unroll
    for (int mt = 0; mt < 2; ++mt)
      #pragma unroll
      for (int nt = 0; nt < 8; ++nt) {
        f32x4 zed = {0.f, 0.f, 0.f, 0.f};
        acc[mt][nt] = zed;
      }
    Frag fa0, fa1;
    #define MFMA8S(S)                                                       \
      _Pragma("unroll")                                                     \
      for (int nt = 0; nt < 8; ++nt) {                                      \
        int idx16 = (nt*16 + lm)*16 + (((S)*4 + lg) ^ (lm & 7));            \
        Frag bf; bf.q = w2l[idx16];                                         \
        acc[0][nt] = __builtin_amdgcn_mfma_f32_16x16x32_f16(fa0.h, bf.h, acc[0][nt], 0, 0, 0); \
        acc[1][nt] = __builtin_amdgcn_mfma_f32_16x16x32_f16(fa1.h, bf.h, acc[1][nt], 0, 0, 0); \
      }
    mg2(Ya00[0], fa0.u[0], fa0.u[1]); mg2(Ya00[1], fa0.u[2], fa0.u[3]);
    mg2(Ya10[0], fa1.u[0], fa1.u[1]); mg2(Ya10[1], fa1.u[2], fa1.u[3]);
    MFMA8S(0)
    mg2(Ya00[2], fa0.u[0], fa0.u[1]); mg2(Ya00[3], fa0.u[2], fa0.u[3]);
    mg2(Ya10[2], fa1.u[0], fa1.u[1]); mg2(Ya10[3], fa1.u[2], fa1.u[3]);
    MFMA8S(1)
    mg2(Ya01[0], fa0.u[0], fa0.u[1]); mg2(Ya01[1], fa0.u[2], fa0.u[3]);
    mg2(Ya11[0], fa1.u[0], fa1.u[1]); mg2(Ya11[1], fa1.u[2], fa1.u[3]);
    MFMA8S(2)
    mg2(Ya01[2], fa0.u[0], fa0.u[1]); mg2(Ya01[3], fa0.u[2], fa0.u[3]);
    mg2(Ya11[2], fa1.u[0], fa1.u[1]); mg2(Ya11[3], fa1.u[2], fa1.u[3]);
    MFMA8S(3)
    #undef MFMA8S
    #pragma unroll
    for (int mt = 0; mt < 2; ++mt) {
      #pragma unroll
      for (int r = 0; r < 4; ++r) {
        float sum = 0.f;
        #pragma unroll
        for (int nt = 0; nt < 8; ++nt) {
          float h2 = fmaxf(acc[mt][nt][r] + b2r[nt], 0.f);
          sum += h2 * w3r[nt];
        }
        sum = dppadd<0xB1>(sum);            // xor1 (quad_perm, VALU pipe)
        sum = dppadd<0x4E>(sum);            // xor2 (quad_perm, VALU pipe)
        sum += __shfl_xor(sum, 4, 64);
        sum += __shfl_xor(sum, 8, 64);
        if (lm == 0) out[ebase + mt*16 + lg*4 + r] = sum + b3v;
      }
    }
    if (!has_next) break;
    tile = next;
    ebase = neb;
    Ya00 = Yb00; Ya01 = Yb01; Ya10 = Yb10; Ya11 = Yb11;
  }
}

extern "C" void kernel_launch(void* const* d_in, const int* in_sizes, int n_in,
                              void* d_out, int out_size, void* d_ws, size_t ws_size,
                              hipStream_t stream) {
  const float* z     = (const float*)d_in[0];
  const int*   ei    = (const int*)d_in[1];
  const float* c     = (const float*)d_in[2];
  const float* W1    = (const float*)d_in[3];
  const float* b1    = (const float*)d_in[4];
  const float* gamma = (const float*)d_in[5];
  const float* beta  = (const float*)d_in[6];
  const float* W2    = (const float*)d_in[7];
  const float* b2    = (const float*)d_in[8];
  const float* W3    = (const float*)d_in[9];
  const float* b3    = (const float*)d_in[10];
  float* out = (float*)d_out;

  const int n_nodes = in_sizes[0] / 64;   // 50000
  const int E       = in_sizes[1] / 2;    // 1600000
  const int NB2 = 1024;

  char* ws = (char*)d_ws;
  const size_t nb128 = (size_t)n_nodes * 128;   // 6.4 MB per table
  unsigned char* U1 = (unsigned char*)ws;
  unsigned char* U2 = U1 + nb128;
  char* p = (char*)(U2 + nb128);
  int* partial        = (int*)p;                 p += (size_t)NB2 * 256 * 4;
  unsigned short* W2t = (unsigned short*)p;      p += 32768;
  float* b2p          = (float*)p;               p += 512;
  float* b2ps         = (float*)p;               p += 512;
  unsigned* gmax1     = (unsigned*)p;            p += 512;
  unsigned* gmax2     = (unsigned*)p;            p += 512;
  unsigned char* H8   = (unsigned char*)p;
  // Tf (f32 projections, 51.2 MB) lives in the H8 region: consumed by
  // k_quant BEFORE k_stats overwrites H8. Union is safe (stream-ordered).
  float* Tf1 = (float*)H8;
  float* Tf2 = Tf1 + (size_t)n_nodes * 128;
  const size_t need = (size_t)((char*)H8 - ws) + (size_t)E * 128;  // ~219 MB
  const bool use_h8 = (ws_size >= need);

  (void)hipMemsetAsync(gmax1, 0, 1024, stream);
  const int npb = (n_nodes + 127) / 128;
  k_nodeproj<<<npb, 256, 0, stream>>>(z, c, W1, b1, gmax1, gmax2,
                                      Tf1, Tf2, n_nodes);
  const int nqb = (n_nodes * 16 + 255) / 256;
  k_quant<<<nqb, 256, 0, stream>>>(Tf1, Tf2, gmax1, gmax2, U1, U2, n_nodes);
  if (use_h8)
    k_stats<1><<<NB2, 512, 0, stream>>>(ei, U1, U2, partial, H8, E, E/16);
  else
    k_stats<0><<<NB2, 512, 0, stream>>>(ei, U1, U2, partial, H8, E, E/16);
  k_finalize<<<1, 1024, 0, stream>>>(partial, NB2, gamma, beta, W2, b2,
                                     gmax1, gmax2, W2t, b2p, b2ps,
                                     1.0 / (double)E);
  if (use_h8)
    k_edge_h8<<<1024, 256, 0, stream>>>(H8, W2t, b2ps, W3, b3, out, E/128);
  else
    k_edge_h8<<<1024, 256, 0, stream>>>(H8, W2t, b2ps, W3, b3, out, E/128);
}

// Round 17
// 344.814 us; speedup vs baseline: 3.6069x; 1.0509x over previous
//
#include <hip/hip_runtime.h>
#include <stdint.h>

typedef _Float16 f16x8 __attribute__((ext_vector_type(8)));
typedef float    f32x4 __attribute__((ext_vector_type(4)));
typedef unsigned u32x4 __attribute__((ext_vector_type(4)));

union Frag { u32x4 q; f16x8 h; unsigned u[4]; };

static __device__ __forceinline__ unsigned short f2h(float f) {
  _Float16 h = (_Float16)f;
  return __builtin_bit_cast(unsigned short, h);
}
// u8 decode: bytes are q+128; h = max(qa+qb-256, 0), int in [0,254]
static __device__ __forceinline__ void dec4i(unsigned a, unsigned b, int* h) {
  unsigned lo = (a & 0x00FF00FFu) + (b & 0x00FF00FFu);
  unsigned hi = ((a >> 8) & 0x00FF00FFu) + ((b >> 8) & 0x00FF00FFu);
  int t0 = (int)(lo & 0xFFFFu) - 256;
  int t1 = (int)(hi & 0xFFFFu) - 256;
  int t2 = (int)(lo >> 16) - 256;
  int t3 = (int)(hi >> 16) - 256;
  h[0] = t0 > 0 ? t0 : 0; h[1] = t1 > 0 ? t1 : 0;
  h[2] = t2 > 0 ? t2 : 0; h[3] = t3 > 0 ? t3 : 0;
}
// magic decode for H8 stream: u32 bytes (h_k0,h_k2,h_k1,h_k3) -> two f16 pairs
// holding 1024+h exactly (offset folded into b2ps).
static __device__ __forceinline__ void mg2(unsigned y, unsigned& w0, unsigned& w1) {
  w0 = (y & 0x00FF00FFu) + 0x64006400u;
  w1 = ((y >> 8) & 0x00FF00FFu) + 0x64006400u;
}
// DPP quad-perm lane-xor add (VALU pipe, not LDS): xor1=0xB1, xor2=0x4E
template<int CTRL>
static __device__ __forceinline__ float dppadd(float s) {
  int v = __builtin_amdgcn_mov_dpp(__builtin_bit_cast(int, s), CTRL, 0xf, 0xf, true);
  return s + __builtin_bit_cast(float, v);
}

// ---------------- kernel 1: per-node projections (feature-per-thread) --
// Single GEMM pass: stores f32 projections Tf1/Tf2 AND per-feature max.
__global__ __launch_bounds__(256) void k_nodeproj(
    const float* __restrict__ z, const float* __restrict__ c,
    const float* __restrict__ W1, const float* __restrict__ b1,
    unsigned* __restrict__ gmax1, unsigned* __restrict__ gmax2,
    float* __restrict__ Tf1, float* __restrict__ Tf2, int n_nodes) {
  __shared__ float zl[128 * 64];   // 32 KB
  const int t = threadIdx.x;
  const int j = t & 127;           // true feature
  const int half = t >> 7;
  const int nb = blockIdx.x * 128;
  {
    const float* zsrc = z + (size_t)nb * 64;
    const int limit = (n_nodes - nb) * 64;
    for (int i = t; i < 2048; i += 256) {
      f32x4 v = {0.f, 0.f, 0.f, 0.f};
      if (i * 4 + 3 < limit) {
        v = *(const f32x4*)(zsrc + i * 4);
      } else {
        #pragma unroll
        for (int q = 0; q < 4; ++q) if (i * 4 + q < limit) v[q] = zsrc[i * 4 + q];
      }
      *(f32x4*)(zl + i * 4) = v;
    }
  }
  float kvj = b1[j];
  #pragma unroll
  for (int q = 0; q < 4; ++q) kvj += c[q] * W1[(128 + q) * 128 + j];
  __syncthreads();

  float wreg[64];
  // ---- half A: T1 (W1 rows 0..63), bias kvj ----
  #pragma unroll
  for (int d = 0; d < 64; ++d) wreg[d] = W1[d * 128 + j];
  float mx = 0.f;
  for (int i = 0; i < 64; ++i) {
    const int n = i * 2 + half;
    const int gn = nb + n;
    float acc = kvj;
    #pragma unroll
    for (int d4 = 0; d4 < 16; ++d4) {
      f32x4 zz = *(const f32x4*)(zl + n * 64 + d4 * 4);
      acc += zz[0]*wreg[d4*4+0] + zz[1]*wreg[d4*4+1]
           + zz[2]*wreg[d4*4+2] + zz[3]*wreg[d4*4+3];
    }
    if (gn < n_nodes) {
      Tf1[(size_t)gn * 128 + j] = acc;
      mx = fmaxf(mx, fabsf(acc));
    }
  }
  atomicMax(&gmax1[j], __float_as_uint(mx));
  // ---- half B: T2 (W1 rows 64..127), no bias ----
  #pragma unroll
  for (int d = 0; d < 64; ++d) wreg[d] = W1[(64 + d) * 128 + j];
  mx = 0.f;
  for (int i = 0; i < 64; ++i) {
    const int n = i * 2 + half;
    const int gn = nb + n;
    float acc = 0.f;
    #pragma unroll
    for (int d4 = 0; d4 < 16; ++d4) {
      f32x4 zz = *(const f32x4*)(zl + n * 64 + d4 * 4);
      acc += zz[0]*wreg[d4*4+0] + zz[1]*wreg[d4*4+1]
           + zz[2]*wreg[d4*4+2] + zz[3]*wreg[d4*4+3];
    }
    if (gn < n_nodes) {
      Tf2[(size_t)gn * 128 + j] = acc;
      mx = fmaxf(mx, fabsf(acc));
    }
  }
  atomicMax(&gmax2[j], __float_as_uint(mx));
}

// ---------------- kernel 1b: streaming quantize Tf -> permuted u8 -----
__global__ __launch_bounds__(256) void k_quant(
    const float* __restrict__ Tf1, const float* __restrict__ Tf2,
    const unsigned* __restrict__ g1, const unsigned* __restrict__ g2,
    unsigned char* __restrict__ U1, unsigned char* __restrict__ U2,
    int n_nodes) {
  const int tid = blockIdx.x * 256 + threadIdx.x;
  const int tot = n_nodes * 8;
  if (tid >= 2 * tot) return;
  const int table = tid >= tot;
  const int r = tid - table * tot;
  const int node = r >> 3, g = r & 7;
  const float* src = (table ? Tf2 : Tf1) + (size_t)node * 128 + g * 16;
  unsigned char* dst = (table ? U2 : U1) + (size_t)node * 128;
  f32x4 v[4];
  #pragma unroll
  for (int q = 0; q < 4; ++q) v[q] = *(const f32x4*)(src + q * 4);
  #pragma unroll
  for (int b = 0; b < 2; ++b) {
    unsigned w0 = 0, w1 = 0;
    #pragma unroll
    for (int k = 0; k < 8; ++k) {
      const int f = g * 16 + b * 8 + k;
      float m = fmaxf(fmaxf(__uint_as_float(g1[f]), __uint_as_float(g2[f])),
                      1e-20f);
      float dij = 127.0f / m;
      float acc = v[b * 2 + (k >> 2)][k & 3];
      int q8 = (int)rintf(acc * dij);
      q8 = q8 > 127 ? 127 : (q8 < -127 ? -127 : q8);
      unsigned by = (unsigned)(q8 + 128);
      if (k < 4) w0 |= by << (8 * k); else w1 |= by << (8 * (k - 4));
    }
    const int off = (((2 * g + b) & 3) * 32) + ((g >> 1) * 8);
    *(unsigned*)(dst + off)     = w0;
    *(unsigned*)(dst + off + 4) = w1;
  }
}

// ---------------- kernel 2: BN stats, 2-deep gather pipeline ----------
template<int WH8>
__global__ __launch_bounds__(512) void k_stats(
    const int* __restrict__ ei, const unsigned char* __restrict__ U1,
    const unsigned char* __restrict__ U2, int* __restrict__ partial,
    unsigned char* __restrict__ H8, int E, int niter16) {
  __shared__ int red[8][256];
  const int t = threadIdx.x;
  const int w = t >> 6, l = t & 63;
  const int es = l >> 3, ch = l & 7;
  int sm[16], sq[16];
  #pragma unroll
  for (int k = 0; k < 16; ++k) { sm[k] = 0; sq[k] = 0; }
  const int nw = gridDim.x * 8;
  int itc = blockIdx.x * 8 + w;
  int itn = itc + nw;
  u32x4 a0c, b0c, a1c, b1c, a0n, b0n, a1n, b1n;
  int ns0 = 0, nd0 = 0, ns1 = 0, nd1 = 0;
  if (itc < niter16) {
    const int e = itc * 16;
    int s0 = ei[e + es],     d0 = ei[E + e + es];
    int s1 = ei[e + 8 + es], d1 = ei[E + e + 8 + es];
    a0c = *(const u32x4*)(U1 + (size_t)s0 * 128 + ch * 16);
    b0c = *(const u32x4*)(U2 + (size_t)d0 * 128 + ch * 16);
    a1c = *(const u32x4*)(U1 + (size_t)s1 * 128 + ch * 16);
    b1c = *(const u32x4*)(U2 + (size_t)d1 * 128 + ch * 16);
  }
  if (itn < niter16) {
    const int e = itn * 16;
    ns0 = ei[e + es];     nd0 = ei[E + e + es];
    ns1 = ei[e + 8 + es]; nd1 = ei[E + e + 8 + es];
  }
  while (itc < niter16) {
    const bool vn = itn < niter16;
    if (vn) {
      a0n = *(const u32x4*)(U1 + (size_t)ns0 * 128 + ch * 16);
      b0n = *(const u32x4*)(U2 + (size_t)nd0 * 128 + ch * 16);
      a1n = *(const u32x4*)(U1 + (size_t)ns1 * 128 + ch * 16);
      b1n = *(const u32x4*)(U2 + (size_t)nd1 * 128 + ch * 16);
      const int it2 = itn + nw;
      if (it2 < niter16) {
        const int e = it2 * 16;
        ns0 = ei[e + es];     nd0 = ei[E + e + es];
        ns1 = ei[e + 8 + es]; nd1 = ei[E + e + 8 + es];
      }
    }
    const int e16 = itc * 16;
    u32x4 o0, o1;
    #pragma unroll
    for (int qq = 0; qq < 4; ++qq) {
      int h[4];
      dec4i(a0c[qq], b0c[qq], h);
      #pragma unroll
      for (int r = 0; r < 4; ++r) { sm[qq*4+r] += h[r]; sq[qq*4+r] += h[r]*h[r]; }
      if (WH8) o0[qq] = (unsigned)h[0] | ((unsigned)h[2] << 8)
                      | ((unsigned)h[1] << 16) | ((unsigned)h[3] << 24);
      dec4i(a1c[qq], b1c[qq], h);
      #pragma unroll
      for (int r = 0; r < 4; ++r) { sm[qq*4+r] += h[r]; sq[qq*4+r] += h[r]*h[r]; }
      if (WH8) o1[qq] = (unsigned)h[0] | ((unsigned)h[2] << 8)
                      | ((unsigned)h[1] << 16) | ((unsigned)h[3] << 24);
    }
    if (WH8) {
      *(u32x4*)(H8 + (size_t)(e16 + es) * 128 + ch * 16)     = o0;
      *(u32x4*)(H8 + (size_t)(e16 + 8 + es) * 128 + ch * 16) = o1;
    }
    if (!vn) break;
    a0c = a0n; b0c = b0n; a1c = a1n; b1c = b1n;
    itc = itn; itn += nw;
  }
  #pragma unroll
  for (int k = 0; k < 16; ++k) {
    sm[k] += __shfl_xor(sm[k], 8, 64);
    sm[k] += __shfl_xor(sm[k], 16, 64);
    sm[k] += __shfl_xor(sm[k], 32, 64);
    sq[k] += __shfl_xor(sq[k], 8, 64);
    sq[k] += __shfl_xor(sq[k], 16, 64);
    sq[k] += __shfl_xor(sq[k], 32, 64);
  }
  if (es == 0) {
    #pragma unroll
    for (int k = 0; k < 16; ++k) {
      int f = ((ch & 1) * 2 + (k >> 3)) * 32 + (ch >> 1) * 8 + (k & 7);
      red[w][f]       = sm[k];
      red[w][128 + f] = sq[k];
    }
  }
  __syncthreads();
  if (t < 256) {
    int s = 0;
    #pragma unroll
    for (int ww = 0; ww < 8; ++ww) s += red[ww][t];
    partial[(size_t)blockIdx.x * 256 + t] = s;
  }
}

// ---------------- kernel 3: finalize BN + fold scale into W2 ----------
__global__ __launch_bounds__(1024) void k_finalize(
    const int* __restrict__ partial, int nb,
    const float* __restrict__ gamma, const float* __restrict__ beta,
    const float* __restrict__ W2, const float* __restrict__ b2,
    const unsigned* __restrict__ gmax1, const unsigned* __restrict__ gmax2,
    unsigned short* __restrict__ W2t, float* __restrict__ b2p,
    float* __restrict__ b2ps, double Einv) {
  __shared__ double redd[4][256];
  __shared__ double stat[256];
  __shared__ float ajd[128], bbj[128];
  __shared__ float bacc[8][128];
  const int t = threadIdx.x;
  const int slot = t & 255, g = t >> 8;
  double s = 0.0;
  for (int b = g; b < nb; b += 4) s += (double)partial[(size_t)b * 256 + slot];
  redd[g][slot] = s;
  __syncthreads();
  if (t < 256) stat[t] = redd[0][t] + redd[1][t] + redd[2][t] + redd[3][t];
  __syncthreads();
  if (t < 128) {
    float m = fmaxf(fmaxf(__uint_as_float(gmax1[t]), __uint_as_float(gmax2[t])),
                    1e-20f);
    double d8 = (double)(m * (1.0f / 127.0f));
    double mean = d8 * stat[t] * Einv;
    double ex2  = d8 * d8 * stat[128 + t] * Einv;
    double var  = ex2 - mean * mean;
    float a = (float)((double)gamma[t] / sqrt(var + 1e-5));
    ajd[t] = a * (float)d8;
    bbj[t] = beta[t] - (float)mean * a;
  }
  __syncthreads();
  for (int cidx = t; cidx < 16384; cidx += 1024) {
    int i = cidx >> 7;
    int j = cidx & 127;
    W2t[j * 128 + i] = f2h(ajd[i] * W2[cidx]);
  }
  {
    const int col = t & 127, g2 = t >> 7;
    float acc = 0.f;
    #pragma unroll
    for (int q = 0; q < 16; ++q) {
      int i = g2 * 16 + q;
      acc += bbj[i] * W2[i * 128 + col];
    }
    bacc[g2][col] = acc;
  }
  __syncthreads();
  if (t < 128) {
    float a = b2[t];
    #pragma unroll
    for (int g3 = 0; g3 < 8; ++g3) a += bacc[g3][t];
    b2p[t] = a;
    float c = 0.f;
    for (int i = 0; i < 128; ++i)
      c += (float)((_Float16)(ajd[i] * W2[i * 128 + t]));
    b2ps[t] = a - 1024.0f * c;
  }
}

// ---------------- kernel 4: streaming MFMA over H8, B in registers ----
// Wave: 16 edges x 128 outputs. All 32 B-fragments (W2t) loop-invariant in
// VGPRs; no LDS at all. Same MFMA/decode/epilogue order as round 16 ->
// bit-identical output.
__global__ __launch_bounds__(256) void k_edge_h8(
    const unsigned char* __restrict__ H8, const unsigned short* __restrict__ W2t,
    const float* __restrict__ b2ps, const float* __restrict__ W3,
    const float* __restrict__ b3, float* __restrict__ out, int ntiles) {
  const int t = threadIdx.x;
  const int w = t >> 6, l = t & 63;
  const int lm = l & 15, lg = l >> 4;
  const int lo32 = lg * 32;
  // loop-invariant B fragments: Bf[nt][s] = W2t row nt*16+lm, k-chunk s*4+lg
  Frag Bf[8][4];
  #pragma unroll
  for (int nt = 0; nt < 8; ++nt)
    #pragma unroll
    for (int s = 0; s < 4; ++s)
      Bf[nt][s].q = *(const u32x4*)((const char*)W2t +
                      (size_t)(nt*16 + lm) * 256 + s*64 + lg*16);
  float b2r[8], w3r[8];
  #pragma unroll
  for (int nt = 0; nt < 8; ++nt) {
    b2r[nt] = b2ps[nt*16 + lm];
    w3r[nt] = W3[nt*16 + lm];
  }
  const float b3v = *b3;
  const int stride = gridDim.x;
  int tile = blockIdx.x;
  if (tile >= ntiles) return;
  int ebase = tile*64 + w*16;
  u32x4 Y0, Y1, N0, N1;   // current / next staged rows (lane lm's edge)
  {
    const unsigned char* r0 = H8 + (size_t)(ebase + lm) * 128 + lo32;
    Y0 = *(const u32x4*)r0;  Y1 = *(const u32x4*)(r0 + 16);
  }
  while (true) {
    const int next = tile + stride;
    const bool has_next = next < ntiles;
    const int pref = has_next ? next : tile;
    const int neb = pref*64 + w*16;
    {
      const unsigned char* n0 = H8 + (size_t)(neb + lm) * 128 + lo32;
      N0 = *(const u32x4*)n0;  N1 = *(const u32x4*)(n0 + 16);
    }
    f32x4 acc[8];
    #pragma unroll
    for (int nt = 0; nt < 8; ++nt) {
      f32x4 zed = {0.f, 0.f, 0.f, 0.f};
      acc[nt] = zed;
    }
    Frag fa;
    #define MFMAS(S)                                                        \
      _Pragma("unroll")                                                     \
      for (int nt = 0; nt < 8; ++nt)                                        \
        acc[nt] = __builtin_amdgcn_mfma_f32_16x16x32_f16(fa.h, Bf[nt][S].h, \
                                                         acc[nt], 0, 0, 0);
    mg2(Y0[0], fa.u[0], fa.u[1]); mg2(Y0[1], fa.u[2], fa.u[3]);
    MFMAS(0)
    mg2(Y0[2], fa.u[0], fa.u[1]); mg2(Y0[3], fa.u[2], fa.u[3]);
    MFMAS(1)
    mg2(Y1[0], fa.u[0], fa.u[1]); mg2(Y1[1], fa.u[2], fa.u[3]);
    MFMAS(2)
    mg2(Y1[2], fa.u[0], fa.u[1]); mg2(Y1[3], fa.u[2], fa.u[3]);
    MFMAS(3)
    #undef MFMAS
    #pragma unroll
    for (int r = 0; r < 4; ++r) {
      float sum = 0.f;
      #pragma unroll
      for (int nt = 0; nt < 8; ++nt) {
        float h2 = fmaxf(acc[nt][r] + b2r[nt], 0.f);
        sum += h2 * w3r[nt];
      }
      sum = dppadd<0xB1>(sum);            // xor1 (quad_perm, VALU pipe)
      sum = dppadd<0x4E>(sum);            // xor2 (quad_perm, VALU pipe)
      sum += __shfl_xor(sum, 4, 64);
      sum += __shfl_xor(sum, 8, 64);
      if (lm == 0) out[ebase + lg*4 + r] = sum + b3v;
    }
    if (!has_next) break;
    tile = next;
    ebase = neb;
    Y0 = N0;  Y1 = N1;
  }
}

extern "C" void kernel_launch(void* const* d_in, const int* in_sizes, int n_in,
                              void* d_out, int out_size, void* d_ws, size_t ws_size,
                              hipStream_t stream) {
  const float* z     = (const float*)d_in[0];
  const int*   ei    = (const int*)d_in[1];
  const float* c     = (const float*)d_in[2];
  const float* W1    = (const float*)d_in[3];
  const float* b1    = (const float*)d_in[4];
  const float* gamma = (const float*)d_in[5];
  const float* beta  = (const float*)d_in[6];
  const float* W2    = (const float*)d_in[7];
  const float* b2    = (const float*)d_in[8];
  const float* W3    = (const float*)d_in[9];
  const float* b3    = (const float*)d_in[10];
  float* out = (float*)d_out;

  const int n_nodes = in_sizes[0] / 64;   // 50000
  const int E       = in_sizes[1] / 2;    // 1600000
  const int NB2 = 1024;

  char* ws = (char*)d_ws;
  const size_t nb128 = (size_t)n_nodes * 128;   // 6.4 MB per table
  unsigned char* U1 = (unsigned char*)ws;
  unsigned char* U2 = U1 + nb128;
  char* p = (char*)(U2 + nb128);
  int* partial        = (int*)p;                 p += (size_t)NB2 * 256 * 4;
  unsigned short* W2t = (unsigned short*)p;      p += 32768;
  float* b2p          = (float*)p;               p += 512;
  float* b2ps         = (float*)p;               p += 512;
  unsigned* gmax1     = (unsigned*)p;            p += 512;
  unsigned* gmax2     = (unsigned*)p;            p += 512;
  unsigned char* H8   = (unsigned char*)p;
  // Tf (f32 projections, 51.2 MB) lives in the H8 region: consumed by
  // k_quant BEFORE k_stats overwrites H8. Union is safe (stream-ordered).
  float* Tf1 = (float*)H8;
  float* Tf2 = Tf1 + (size_t)n_nodes * 128;
  const size_t need = (size_t)((char*)H8 - ws) + (size_t)E * 128;  // ~219 MB
  const bool use_h8 = (ws_size >= need);

  (void)hipMemsetAsync(gmax1, 0, 1024, stream);
  const int npb = (n_nodes + 127) / 128;
  k_nodeproj<<<npb, 256, 0, stream>>>(z, c, W1, b1, gmax1, gmax2,
                                      Tf1, Tf2, n_nodes);
  const int nqb = (n_nodes * 16 + 255) / 256;
  k_quant<<<nqb, 256, 0, stream>>>(Tf1, Tf2, gmax1, gmax2, U1, U2, n_nodes);
  if (use_h8)
    k_stats<1><<<NB2, 512, 0, stream>>>(ei, U1, U2, partial, H8, E, E/16);
  else
    k_stats<0><<<NB2, 512, 0, stream>>>(ei, U1, U2, partial, H8, E, E/16);
  k_finalize<<<1, 1024, 0, stream>>>(partial, NB2, gamma, beta, W2, b2,
                                     gmax1, gmax2, W2t, b2p, b2ps,
                                     1.0 / (double)E);
  k_edge_h8<<<512, 256, 0, stream>>>(H8, W2t, b2ps, W3, b3, out, E/64);
}

// Round 18
// 272.565 us; speedup vs baseline: 4.5630x; 1.2651x over previous
//
#include <hip/hip_runtime.h>
#include <stdint.h>

typedef _Float16 f16x8 __attribute__((ext_vector_type(8)));
typedef float    f32x4 __attribute__((ext_vector_type(4)));
typedef unsigned u32x4 __attribute__((ext_vector_type(4)));

union Frag { u32x4 q; f16x8 h; unsigned u[4]; };

static __device__ __forceinline__ unsigned short f2h(float f) {
  _Float16 h = (_Float16)f;
  return __builtin_bit_cast(unsigned short, h);
}
// u8 decode: bytes are q+128; h = max(qa+qb-256, 0), int in [0,254]
static __device__ __forceinline__ void dec4i(unsigned a, unsigned b, int* h) {
  unsigned lo = (a & 0x00FF00FFu) + (b & 0x00FF00FFu);
  unsigned hi = ((a >> 8) & 0x00FF00FFu) + ((b >> 8) & 0x00FF00FFu);
  int t0 = (int)(lo & 0xFFFFu) - 256;
  int t1 = (int)(hi & 0xFFFFu) - 256;
  int t2 = (int)(lo >> 16) - 256;
  int t3 = (int)(hi >> 16) - 256;
  h[0] = t0 > 0 ? t0 : 0; h[1] = t1 > 0 ? t1 : 0;
  h[2] = t2 > 0 ? t2 : 0; h[3] = t3 > 0 ? t3 : 0;
}
// magic decode for H8 stream: u32 bytes (h_k0,h_k2,h_k1,h_k3) -> two f16 pairs
// holding 1024+h exactly (offset folded into b2ps).
static __device__ __forceinline__ void mg2(unsigned y, unsigned& w0, unsigned& w1) {
  w0 = (y & 0x00FF00FFu) + 0x64006400u;
  w1 = ((y >> 8) & 0x00FF00FFu) + 0x64006400u;
}
// DPP quad-perm lane-xor add (VALU pipe, not LDS): xor1=0xB1, xor2=0x4E
template<int CTRL>
static __device__ __forceinline__ float dppadd(float s) {
  int v = __builtin_amdgcn_mov_dpp(__builtin_bit_cast(int, s), CTRL, 0xf, 0xf, true);
  return s + __builtin_bit_cast(float, v);
}

// ---------------- kernel 1: per-node projections (feature-per-thread) --
// Single GEMM pass: stores f32 projections Tf1/Tf2 AND per-feature max.
__global__ __launch_bounds__(256) void k_nodeproj(
    const float* __restrict__ z, const float* __restrict__ c,
    const float* __restrict__ W1, const float* __restrict__ b1,
    unsigned* __restrict__ gmax1, unsigned* __restrict__ gmax2,
    float* __restrict__ Tf1, float* __restrict__ Tf2, int n_nodes) {
  __shared__ float zl[128 * 64];   // 32 KB
  const int t = threadIdx.x;
  const int j = t & 127;           // true feature
  const int half = t >> 7;
  const int nb = blockIdx.x * 128;
  {
    const float* zsrc = z + (size_t)nb * 64;
    const int limit = (n_nodes - nb) * 64;
    for (int i = t; i < 2048; i += 256) {
      f32x4 v = {0.f, 0.f, 0.f, 0.f};
      if (i * 4 + 3 < limit) {
        v = *(const f32x4*)(zsrc + i * 4);
      } else {
        #pragma unroll
        for (int q = 0; q < 4; ++q) if (i * 4 + q < limit) v[q] = zsrc[i * 4 + q];
      }
      *(f32x4*)(zl + i * 4) = v;
    }
  }
  float kvj = b1[j];
  #pragma unroll
  for (int q = 0; q < 4; ++q) kvj += c[q] * W1[(128 + q) * 128 + j];
  __syncthreads();

  float wreg[64];
  // ---- half A: T1 (W1 rows 0..63), bias kvj ----
  #pragma unroll
  for (int d = 0; d < 64; ++d) wreg[d] = W1[d * 128 + j];
  float mx = 0.f;
  for (int i = 0; i < 64; ++i) {
    const int n = i * 2 + half;
    const int gn = nb + n;
    float acc = kvj;
    #pragma unroll
    for (int d4 = 0; d4 < 16; ++d4) {
      f32x4 zz = *(const f32x4*)(zl + n * 64 + d4 * 4);
      acc += zz[0]*wreg[d4*4+0] + zz[1]*wreg[d4*4+1]
           + zz[2]*wreg[d4*4+2] + zz[3]*wreg[d4*4+3];
    }
    if (gn < n_nodes) {
      Tf1[(size_t)gn * 128 + j] = acc;
      mx = fmaxf(mx, fabsf(acc));
    }
  }
  atomicMax(&gmax1[j], __float_as_uint(mx));
  // ---- half B: T2 (W1 rows 64..127), no bias ----
  #pragma unroll
  for (int d = 0; d < 64; ++d) wreg[d] = W1[(64 + d) * 128 + j];
  mx = 0.f;
  for (int i = 0; i < 64; ++i) {
    const int n = i * 2 + half;
    const int gn = nb + n;
    float acc = 0.f;
    #pragma unroll
    for (int d4 = 0; d4 < 16; ++d4) {
      f32x4 zz = *(const f32x4*)(zl + n * 64 + d4 * 4);
      acc += zz[0]*wreg[d4*4+0] + zz[1]*wreg[d4*4+1]
           + zz[2]*wreg[d4*4+2] + zz[3]*wreg[d4*4+3];
    }
    if (gn < n_nodes) {
      Tf2[(size_t)gn * 128 + j] = acc;
      mx = fmaxf(mx, fabsf(acc));
    }
  }
  atomicMax(&gmax2[j], __float_as_uint(mx));
}

// ---------------- kernel 1b: streaming quantize Tf -> permuted u8 -----
__global__ __launch_bounds__(256) void k_quant(
    const float* __restrict__ Tf1, const float* __restrict__ Tf2,
    const unsigned* __restrict__ g1, const unsigned* __restrict__ g2,
    unsigned char* __restrict__ U1, unsigned char* __restrict__ U2,
    int n_nodes) {
  const int tid = blockIdx.x * 256 + threadIdx.x;
  const int tot = n_nodes * 8;
  if (tid >= 2 * tot) return;
  const int table = tid >= tot;
  const int r = tid - table * tot;
  const int node = r >> 3, g = r & 7;
  const float* src = (table ? Tf2 : Tf1) + (size_t)node * 128 + g * 16;
  unsigned char* dst = (table ? U2 : U1) + (size_t)node * 128;
  f32x4 v[4];
  #pragma unroll
  for (int q = 0; q < 4; ++q) v[q] = *(const f32x4*)(src + q * 4);
  #pragma unroll
  for (int b = 0; b < 2; ++b) {
    unsigned w0 = 0, w1 = 0;
    #pragma unroll
    for (int k = 0; k < 8; ++k) {
      const int f = g * 16 + b * 8 + k;
      float m = fmaxf(fmaxf(__uint_as_float(g1[f]), __uint_as_float(g2[f])),
                      1e-20f);
      float dij = 127.0f / m;
      float acc = v[b * 2 + (k >> 2)][k & 3];
      int q8 = (int)rintf(acc * dij);
      q8 = q8 > 127 ? 127 : (q8 < -127 ? -127 : q8);
      unsigned by = (unsigned)(q8 + 128);
      if (k < 4) w0 |= by << (8 * k); else w1 |= by << (8 * (k - 4));
    }
    const int off = (((2 * g + b) & 3) * 32) + ((g >> 1) * 8);
    *(unsigned*)(dst + off)     = w0;
    *(unsigned*)(dst + off + 4) = w1;
  }
}

// ---------------- kernel 2: BN stats, 2-deep gather pipeline ----------
// Block-level int sums -> ONE 64-bit atomicAdd per slot (integer adds are
// order-independent -> bitwise deterministic).
template<int WH8>
__global__ __launch_bounds__(512) void k_stats(
    const int* __restrict__ ei, const unsigned char* __restrict__ U1,
    const unsigned char* __restrict__ U2,
    unsigned long long* __restrict__ gstat,
    unsigned char* __restrict__ H8, int E, int niter16) {
  __shared__ int red[8][256];
  const int t = threadIdx.x;
  const int w = t >> 6, l = t & 63;
  const int es = l >> 3, ch = l & 7;
  int sm[16], sq[16];
  #pragma unroll
  for (int k = 0; k < 16; ++k) { sm[k] = 0; sq[k] = 0; }
  const int nw = gridDim.x * 8;
  int itc = blockIdx.x * 8 + w;
  int itn = itc + nw;
  u32x4 a0c, b0c, a1c, b1c, a0n, b0n, a1n, b1n;
  int ns0 = 0, nd0 = 0, ns1 = 0, nd1 = 0;
  if (itc < niter16) {
    const int e = itc * 16;
    int s0 = ei[e + es],     d0 = ei[E + e + es];
    int s1 = ei[e + 8 + es], d1 = ei[E + e + 8 + es];
    a0c = *(const u32x4*)(U1 + (size_t)s0 * 128 + ch * 16);
    b0c = *(const u32x4*)(U2 + (size_t)d0 * 128 + ch * 16);
    a1c = *(const u32x4*)(U1 + (size_t)s1 * 128 + ch * 16);
    b1c = *(const u32x4*)(U2 + (size_t)d1 * 128 + ch * 16);
  }
  if (itn < niter16) {
    const int e = itn * 16;
    ns0 = ei[e + es];     nd0 = ei[E + e + es];
    ns1 = ei[e + 8 + es]; nd1 = ei[E + e + 8 + es];
  }
  while (itc < niter16) {
    const bool vn = itn < niter16;
    if (vn) {
      a0n = *(const u32x4*)(U1 + (size_t)ns0 * 128 + ch * 16);
      b0n = *(const u32x4*)(U2 + (size_t)nd0 * 128 + ch * 16);
      a1n = *(const u32x4*)(U1 + (size_t)ns1 * 128 + ch * 16);
      b1n = *(const u32x4*)(U2 + (size_t)nd1 * 128 + ch * 16);
      const int it2 = itn + nw;
      if (it2 < niter16) {
        const int e = it2 * 16;
        ns0 = ei[e + es];     nd0 = ei[E + e + es];
        ns1 = ei[e + 8 + es]; nd1 = ei[E + e + 8 + es];
      }
    }
    const int e16 = itc * 16;
    u32x4 o0, o1;
    #pragma unroll
    for (int qq = 0; qq < 4; ++qq) {
      int h[4];
      dec4i(a0c[qq], b0c[qq], h);
      #pragma unroll
      for (int r = 0; r < 4; ++r) { sm[qq*4+r] += h[r]; sq[qq*4+r] += h[r]*h[r]; }
      if (WH8) o0[qq] = (unsigned)h[0] | ((unsigned)h[2] << 8)
                      | ((unsigned)h[1] << 16) | ((unsigned)h[3] << 24);
      dec4i(a1c[qq], b1c[qq], h);
      #pragma unroll
      for (int r = 0; r < 4; ++r) { sm[qq*4+r] += h[r]; sq[qq*4+r] += h[r]*h[r]; }
      if (WH8) o1[qq] = (unsigned)h[0] | ((unsigned)h[2] << 8)
                      | ((unsigned)h[1] << 16) | ((unsigned)h[3] << 24);
    }
    if (WH8) {
      *(u32x4*)(H8 + (size_t)(e16 + es) * 128 + ch * 16)     = o0;
      *(u32x4*)(H8 + (size_t)(e16 + 8 + es) * 128 + ch * 16) = o1;
    }
    if (!vn) break;
    a0c = a0n; b0c = b0n; a1c = a1n; b1c = b1n;
    itc = itn; itn += nw;
  }
  #pragma unroll
  for (int k = 0; k < 16; ++k) {
    sm[k] += __shfl_xor(sm[k], 8, 64);
    sm[k] += __shfl_xor(sm[k], 16, 64);
    sm[k] += __shfl_xor(sm[k], 32, 64);
    sq[k] += __shfl_xor(sq[k], 8, 64);
    sq[k] += __shfl_xor(sq[k], 16, 64);
    sq[k] += __shfl_xor(sq[k], 32, 64);
  }
  if (es == 0) {
    #pragma unroll
    for (int k = 0; k < 16; ++k) {
      int f = ((ch & 1) * 2 + (k >> 3)) * 32 + (ch >> 1) * 8 + (k & 7);
      red[w][f]       = sm[k];
      red[w][128 + f] = sq[k];
    }
  }
  __syncthreads();
  if (t < 256) {
    long long s = 0;
    #pragma unroll
    for (int ww = 0; ww < 8; ++ww) s += red[ww][t];
    atomicAdd(&gstat[t], (unsigned long long)s);
  }
}

// ---------------- kernel 3: finalize BN + fold scale into W2 ----------
__global__ __launch_bounds__(1024) void k_finalize(
    const unsigned long long* __restrict__ gstat,
    const float* __restrict__ gamma, const float* __restrict__ beta,
    const float* __restrict__ W2, const float* __restrict__ b2,
    const unsigned* __restrict__ gmax1, const unsigned* __restrict__ gmax2,
    unsigned short* __restrict__ W2t, float* __restrict__ b2p,
    float* __restrict__ b2ps, double Einv) {
  __shared__ float ajd[128], bbj[128];
  __shared__ float bacc[8][128];
  const int t = threadIdx.x;
  if (t < 128) {
    float m = fmaxf(fmaxf(__uint_as_float(gmax1[t]), __uint_as_float(gmax2[t])),
                    1e-20f);
    double d8 = (double)(m * (1.0f / 127.0f));
    double mean = d8 * (double)gstat[t] * Einv;
    double ex2  = d8 * d8 * (double)gstat[128 + t] * Einv;
    double var  = ex2 - mean * mean;
    float a = (float)((double)gamma[t] / sqrt(var + 1e-5));
    ajd[t] = a * (float)d8;
    bbj[t] = beta[t] - (float)mean * a;
  }
  __syncthreads();
  for (int cidx = t; cidx < 16384; cidx += 1024) {
    int i = cidx >> 7;
    int j = cidx & 127;
    W2t[j * 128 + i] = f2h(ajd[i] * W2[cidx]);
  }
  {
    const int col = t & 127, g2 = t >> 7;
    float acc = 0.f;
    #pragma unroll
    for (int q = 0; q < 16; ++q) {
      int i = g2 * 16 + q;
      acc += bbj[i] * W2[i * 128 + col];
    }
    bacc[g2][col] = acc;
  }
  __syncthreads();
  if (t < 128) {
    float a = b2[t];
    #pragma unroll
    for (int g3 = 0; g3 < 8; ++g3) a += bacc[g3][t];
    b2p[t] = a;
    float c = 0.f;
    for (int i = 0; i < 128; ++i)
      c += (float)((_Float16)(ajd[i] * W2[i * 128 + t]));
    b2ps[t] = a - 1024.0f * c;
  }
}

// ---------------- kernel 4: streaming MFMA over H8, B in registers ----
__global__ __launch_bounds__(256) void k_edge_h8(
    const unsigned char* __restrict__ H8, const unsigned short* __restrict__ W2t,
    const float* __restrict__ b2ps, const float* __restrict__ W3,
    const float* __restrict__ b3, float* __restrict__ out, int ntiles) {
  const int t = threadIdx.x;
  const int w = t >> 6, l = t & 63;
  const int lm = l & 15, lg = l >> 4;
  const int lo32 = lg * 32;
  // loop-invariant B fragments: Bf[nt][s] = W2t row nt*16+lm, k-chunk s*4+lg
  Frag Bf[8][4];
  #pragma unroll
  for (int nt = 0; nt < 8; ++nt)
    #pragma unroll
    for (int s = 0; s < 4; ++s)
      Bf[nt][s].q = *(const u32x4*)((const char*)W2t +
                      (size_t)(nt*16 + lm) * 256 + s*64 + lg*16);
  float b2r[8], w3r[8];
  #pragma unroll
  for (int nt = 0; nt < 8; ++nt) {
    b2r[nt] = b2ps[nt*16 + lm];
    w3r[nt] = W3[nt*16 + lm];
  }
  const float b3v = *b3;
  const int stride = gridDim.x;
  int tile = blockIdx.x;
  if (tile >= ntiles) return;
  int ebase = tile*64 + w*16;
  u32x4 Y0, Y1, N0, N1;   // current / next staged rows (lane lm's edge)
  {
    const unsigned char* r0 = H8 + (size_t)(ebase + lm) * 128 + lo32;
    Y0 = *(const u32x4*)r0;  Y1 = *(const u32x4*)(r0 + 16);
  }
  while (true) {
    const int next = tile + stride;
    const bool has_next = next < ntiles;
    const int pref = has_next ? next : tile;
    const int neb = pref*64 + w*16;
    {
      const unsigned char* n0 = H8 + (size_t)(neb + lm) * 128 + lo32;
      N0 = *(const u32x4*)n0;  N1 = *(const u32x4*)(n0 + 16);
    }
    f32x4 acc[8];
    #pragma unroll
    for (int nt = 0; nt < 8; ++nt) {
      f32x4 zed = {0.f, 0.f, 0.f, 0.f};
      acc[nt] = zed;
    }
    Frag fa;
    #define MFMAS(S)                                                        \
      _Pragma("unroll")                                                     \
      for (int nt = 0; nt < 8; ++nt)                                        \
        acc[nt] = __builtin_amdgcn_mfma_f32_16x16x32_f16(fa.h, Bf[nt][S].h, \
                                                         acc[nt], 0, 0, 0);
    mg2(Y0[0], fa.u[0], fa.u[1]); mg2(Y0[1], fa.u[2], fa.u[3]);
    MFMAS(0)
    mg2(Y0[2], fa.u[0], fa.u[1]); mg2(Y0[3], fa.u[2], fa.u[3]);
    MFMAS(1)
    mg2(Y1[0], fa.u[0], fa.u[1]); mg2(Y1[1], fa.u[2], fa.u[3]);
    MFMAS(2)
    mg2(Y1[2], fa.u[0], fa.u[1]); mg2(Y1[3], fa.u[2], fa.u[3]);
    MFMAS(3)
    #undef MFMAS
    #pragma unroll
    for (int r = 0; r < 4; ++r) {
      float sum = 0.f;
      #pragma unroll
      for (int nt = 0; nt < 8; ++nt) {
        float h2 = fmaxf(acc[nt][r] + b2r[nt], 0.f);
        sum += h2 * w3r[nt];
      }
      sum = dppadd<0xB1>(sum);            // xor1 (quad_perm, VALU pipe)
      sum = dppadd<0x4E>(sum);            // xor2 (quad_perm, VALU pipe)
      sum += __shfl_xor(sum, 4, 64);
      sum += __shfl_xor(sum, 8, 64);
      if (lm == 0) out[ebase + lg*4 + r] = sum + b3v;
    }
    if (!has_next) break;
    tile = next;
    ebase = neb;
    Y0 = N0;  Y1 = N1;
  }
}

extern "C" void kernel_launch(void* const* d_in, const int* in_sizes, int n_in,
                              void* d_out, int out_size, void* d_ws, size_t ws_size,
                              hipStream_t stream) {
  const float* z     = (const float*)d_in[0];
  const int*   ei    = (const int*)d_in[1];
  const float* c     = (const float*)d_in[2];
  const float* W1    = (const float*)d_in[3];
  const float* b1    = (const float*)d_in[4];
  const float* gamma = (const float*)d_in[5];
  const float* beta  = (const float*)d_in[6];
  const float* W2    = (const float*)d_in[7];
  const float* b2    = (const float*)d_in[8];
  const float* W3    = (const float*)d_in[9];
  const float* b3    = (const float*)d_in[10];
  float* out = (float*)d_out;

  const int n_nodes = in_sizes[0] / 64;   // 50000
  const int E       = in_sizes[1] / 2;    // 1600000
  const int NB2 = 1024;

  char* ws = (char*)d_ws;
  const size_t nb128 = (size_t)n_nodes * 128;   // 6.4 MB per table
  unsigned char* U1 = (unsigned char*)ws;
  unsigned char* U2 = U1 + nb128;
  char* p = (char*)(U2 + nb128);
  unsigned short* W2t = (unsigned short*)p;      p += 32768;
  float* b2p          = (float*)p;               p += 512;
  float* b2ps         = (float*)p;               p += 512;
  unsigned* gmax1     = (unsigned*)p;            p += 512;
  unsigned* gmax2     = (unsigned*)p;            p += 512;
  unsigned long long* gstat = (unsigned long long*)p;  p += 2048;
  unsigned char* H8   = (unsigned char*)p;
  // Tf (f32 projections, 51.2 MB) lives in the H8 region: consumed by
  // k_quant BEFORE k_stats overwrites H8. Union is safe (stream-ordered).
  float* Tf1 = (float*)H8;
  float* Tf2 = Tf1 + (size_t)n_nodes * 128;
  const size_t need = (size_t)((char*)H8 - ws) + (size_t)E * 128;  // ~218 MB
  const bool use_h8 = (ws_size >= need);

  // zero gmax1(512) + gmax2(512) + gstat(2048) in one contiguous memset
  (void)hipMemsetAsync(gmax1, 0, 3072, stream);
  const int npb = (n_nodes + 127) / 128;
  k_nodeproj<<<npb, 256, 0, stream>>>(z, c, W1, b1, gmax1, gmax2,
                                      Tf1, Tf2, n_nodes);
  const int nqb = (n_nodes * 16 + 255) / 256;
  k_quant<<<nqb, 256, 0, stream>>>(Tf1, Tf2, gmax1, gmax2, U1, U2, n_nodes);
  if (use_h8)
    k_stats<1><<<NB2, 512, 0, stream>>>(ei, U1, U2, gstat, H8, E, E/16);
  else
    k_stats<0><<<NB2, 512, 0, stream>>>(ei, U1, U2, gstat, H8, E, E/16);
  k_finalize<<<1, 1024, 0, stream>>>(gstat, gamma, beta, W2, b2,
                                     gmax1, gmax2, W2t, b2p, b2ps,
                                     1.0 / (double)E);
  k_edge_h8<<<512, 256, 0, stream>>>(H8, W2t, b2ps, W3, b3, out, E/64);
}